// Round 1
// baseline (408.114 us; speedup 1.0000x reference)
//
#include <hip/hip_runtime.h>
#include <hip/hip_bf16.h>
#include <math.h>

#define B_ 2
#define T_ 2048
#define D_ 1024
#define H_ 16
#define DH_ 64

typedef __bf16 bf16_t;
typedef bf16_t bf16x8 __attribute__((ext_vector_type(8)));
typedef bf16_t bf16x4 __attribute__((ext_vector_type(4)));
typedef float f32x4 __attribute__((ext_vector_type(4)));

typedef __attribute__((address_space(1))) const void gas_void;
typedef __attribute__((address_space(3))) void las_void;

__device__ __forceinline__ void gld16(const void* g, void* l) {
    __builtin_amdgcn_global_load_lds((gas_void*)g, (las_void*)l, 16, 0, 0);
}

// ---------------- fp32 -> bf16 convert ----------------
__global__ __launch_bounds__(256) void cvt_bf16(const float* __restrict__ in,
                                                bf16_t* __restrict__ out, int n) {
    int i = (blockIdx.x * 256 + threadIdx.x) * 4;
    if (i >= n) return;
    float4 f = *(const float4*)(in + i);
    bf16x4 v = { (bf16_t)f.x, (bf16_t)f.y, (bf16_t)f.z, (bf16_t)f.w };
    *(bf16x4*)(out + i) = v;
}

// ---------------- 128x128 GEMM, C = A @ B^T (+bias, + fused epilogue) ---------
// A: [M][K] bf16 row-major, Bw: [N][K] bf16 row-major.
// EPI=0: qkv -> RoPE(q,k) scatter to q[BH][T][64], k[BH][T][64], vT[BH][64][T]
// EPI=1: fp32 store with bias
template<int EPI>
__global__ __launch_bounds__(256) void gemm128(const bf16_t* __restrict__ A,
                                               const bf16_t* __restrict__ Bw,
                                               const float* __restrict__ bias,
                                               bf16_t* __restrict__ q_out,
                                               bf16_t* __restrict__ k_out,
                                               bf16_t* __restrict__ vt_out,
                                               float* __restrict__ f_out,
                                               int K, int N) {
    __shared__ char As[8192];   // [128][32] bf16
    __shared__ char Bs[8192];
    int tid = threadIdx.x;
    int lane = tid & 63, wid = tid >> 6;
    int wr = wid >> 1, wc = wid & 1;
    int lr = lane & 15, lk = lane >> 4;

    f32x4 acc[4][4];
    f32x4 z = {0.f, 0.f, 0.f, 0.f};
#pragma unroll
    for (int i = 0; i < 4; i++)
#pragma unroll
        for (int j = 0; j < 4; j++) acc[i][j] = z;

    const char* Ab = (const char*)(A + (size_t)blockIdx.y * 128 * K);
    const char* Bb = (const char*)(Bw + (size_t)blockIdx.x * 128 * K);
    const int rowstride = K * 2;

    for (int k0 = 0; k0 < K * 2; k0 += 64) {  // k0 in bytes (BK=32 elems)
#pragma unroll
        for (int c = 0; c < 2; c++) {
            int o = c * 4096 + tid * 16;      // byte offset inside 8KB tile
            int r = o >> 6, cb = o & 63;      // row, in-row byte
            gld16(Ab + (size_t)r * rowstride + k0 + cb, As + o);
            gld16(Bb + (size_t)r * rowstride + k0 + cb, Bs + o);
        }
        __syncthreads();
        bf16x8 af[4], bfr[4];
#pragma unroll
        for (int m = 0; m < 4; m++)
            af[m] = *(const bf16x8*)(As + (wr * 64 + m * 16 + lr) * 64 + lk * 16);
#pragma unroll
        for (int n = 0; n < 4; n++)
            bfr[n] = *(const bf16x8*)(Bs + (wc * 64 + n * 16 + lr) * 64 + lk * 16);
#pragma unroll
        for (int m = 0; m < 4; m++)
#pragma unroll
            for (int n = 0; n < 4; n++)
                acc[m][n] = __builtin_amdgcn_mfma_f32_16x16x32_bf16(af[m], bfr[n], acc[m][n], 0, 0, 0);
        __syncthreads();
    }

    // epilogue: C layout col = lane&15, row = (lane>>4)*4 + j
    int m_base = blockIdx.y * 128 + wr * 64;
    int n_base = blockIdx.x * 128 + wc * 64;
#pragma unroll
    for (int m = 0; m < 4; m++) {
        int gm0 = m_base + m * 16 + lk * 4;
#pragma unroll
        for (int n = 0; n < 4; n++) {
            int nc = n_base + n * 16 + lr;
            float bv = bias[nc];
            float v[4];
#pragma unroll
            for (int j = 0; j < 4; j++) v[j] = acc[m][n][j] + bv;
            if (EPI == 1) {
#pragma unroll
                for (int j = 0; j < 4; j++)
                    f_out[(size_t)(gm0 + j) * N + nc] = v[j];
            } else {
                int which = nc >> 10;          // 0=q 1=k 2=v  (uniform per fragment)
                int d = nc & 1023;
                int h = d >> 6, dh = d & 63;
                int b = gm0 >> 11, t0 = gm0 & 2047;
                int bh = b * H_ + h;
                if (which == 2) {
                    bf16x4 pk = { (bf16_t)v[0], (bf16_t)v[1], (bf16_t)v[2], (bf16_t)v[3] };
                    *(bf16x4*)(vt_out + ((size_t)bh * DH_ + dh) * T_ + t0) = pk;
                } else {
                    // RoPE: partner element (dh^1) lives in lane^1, same j
                    float invf = exp2f(-(float)(dh >> 1) * 0.4152410118609203f); // log2(1e4)/32
                    bool even = ((dh & 1) == 0);
                    bf16_t* dst = (which == 0) ? q_out : k_out;
#pragma unroll
                    for (int j = 0; j < 4; j++) {
                        float p = __shfl_xor(v[j], 1);
                        float ang = (float)(t0 + j) * invf;
                        float sn, cs;
                        sincosf(ang, &sn, &cs);
                        float r = even ? (v[j] * cs - p * sn) : (v[j] * cs + p * sn);
                        dst[((size_t)bh * T_ + t0 + j) * DH_ + dh] = (bf16_t)r;
                    }
                }
            }
        }
    }
}

// ---------------- flash attention: 1 block = (bh, 64 q rows), 4 waves ---------
__global__ __launch_bounds__(256) void attn64(const bf16_t* __restrict__ Q,
                                              const bf16_t* __restrict__ K,
                                              const bf16_t* __restrict__ Vt,
                                              bf16_t* __restrict__ Ao) {
    __shared__ char Ks[8192];      // [64 kv][64 dh] bf16, XOR-swizzled
    __shared__ char Vs[8192];      // [64 d][64 kv]  bf16, XOR-swizzled
    __shared__ char Ps[4][2048];   // per-wave P [16 q][64 kv] bf16, swizzled

    int tid = threadIdx.x;
    int lane = tid & 63, wid = tid >> 6;
    int lr = lane & 15, lk = lane >> 4;
    int bh = blockIdx.x >> 5, qt = blockIdx.x & 31;
    int q0 = qt * 64;

    const bf16_t* Qp = Q + ((size_t)bh * T_ + q0 + wid * 16 + lr) * DH_;
    bf16x8 qf0 = *(const bf16x8*)(Qp + lk * 8);
    bf16x8 qf1 = *(const bf16x8*)(Qp + 32 + lk * 8);

    f32x4 zz = {0.f, 0.f, 0.f, 0.f};
    f32x4 oacc[4];
#pragma unroll
    for (int dt = 0; dt < 4; dt++) oacc[dt] = zz;
    float mrun[4], lsum[4];
    int qrow[4];
#pragma unroll
    for (int j = 0; j < 4; j++) {
        mrun[j] = -__builtin_inff();
        lsum[j] = 0.f;
        qrow[j] = q0 + wid * 16 + lk * 4 + j;
    }

    const char* Kbase = (const char*)(K + (size_t)bh * T_ * DH_);
    const char* Vbase = (const char*)(Vt + (size_t)bh * DH_ * T_);
    const float LOG2E = 1.44269504088896f;

    for (int s = 0; s <= qt; ++s) {
        int kv0 = s * 64;
        const char* Kg = Kbase + (size_t)kv0 * (DH_ * 2);
#pragma unroll
        for (int c = 0; c < 2; c++) {
            int o = c * 4096 + tid * 16;
            int r = o >> 7;                       // tile row (128B rows)
            int g = o ^ ((r & 7) << 4);           // pre-swizzled source (involution)
            gld16(Kg + g, Ks + o);                // K tile is contiguous 8KB
            gld16(Vbase + (size_t)r * (T_ * 2) + kv0 * 2 + (g & 127), Vs + o);
        }
        __syncthreads();

        // ---- QK^T (S rows=q, cols=kv), mask, scale ----
        float sf[4][4];
#pragma unroll
        for (int kt = 0; kt < 4; kt++) {
            f32x4 sacc = zz;
            int row = kt * 16 + lr;
            int key = (row & 7) << 4;
            bf16x8 kf0 = *(const bf16x8*)(Ks + ((row * 128 + lk * 16) ^ key));
            bf16x8 kf1 = *(const bf16x8*)(Ks + ((row * 128 + 64 + lk * 16) ^ key));
            sacc = __builtin_amdgcn_mfma_f32_16x16x32_bf16(qf0, kf0, sacc, 0, 0, 0);
            sacc = __builtin_amdgcn_mfma_f32_16x16x32_bf16(qf1, kf1, sacc, 0, 0, 0);
            int kvc = kv0 + kt * 16 + lr;
#pragma unroll
            for (int j = 0; j < 4; j++) {
                float sv = sacc[j] * 0.125f;  // 1/sqrt(64)
                sf[kt][j] = (kvc <= qrow[j]) ? sv : -__builtin_inff();
            }
        }

        // ---- online softmax ----
        float mnew[4], fac[4], rs[4];
#pragma unroll
        for (int j = 0; j < 4; j++) {
            float mx = fmaxf(fmaxf(sf[0][j], sf[1][j]), fmaxf(sf[2][j], sf[3][j]));
#pragma unroll
            for (int dd = 1; dd < 16; dd <<= 1) mx = fmaxf(mx, __shfl_xor(mx, dd));
            mnew[j] = fmaxf(mrun[j], mx);
            fac[j] = exp2f((mrun[j] - mnew[j]) * LOG2E);
            mrun[j] = mnew[j];
            rs[j] = 0.f;
        }
        f32x4 facv = { fac[0], fac[1], fac[2], fac[3] };
#pragma unroll
        for (int dt = 0; dt < 4; dt++) oacc[dt] *= facv;
#pragma unroll
        for (int kt = 0; kt < 4; kt++) {
#pragma unroll
            for (int j = 0; j < 4; j++) {
                float p = exp2f((sf[kt][j] - mnew[j]) * LOG2E);
                rs[j] += p;
                int prow = lk * 4 + j;
                int addr = (prow * 128 + (kt * 16 + lr) * 2) ^ ((prow & 7) << 4);
                *(bf16_t*)(&Ps[wid][addr]) = (bf16_t)p;
            }
        }
#pragma unroll
        for (int j = 0; j < 4; j++) {
#pragma unroll
            for (int dd = 1; dd < 16; dd <<= 1) rs[j] += __shfl_xor(rs[j], dd);
            lsum[j] = lsum[j] * fac[j] + rs[j];
        }
        __syncthreads();   // P visible; QK reads of Ks done

        // ---- PV:  O += P @ V  (Vt rows are d, so B-frag is contiguous) ----
#pragma unroll
        for (int hk = 0; hk < 2; hk++) {
            bf16x8 pf = *(const bf16x8*)(&Ps[wid][(lr * 128 + hk * 64 + lk * 16) ^ ((lr & 7) << 4)]);
#pragma unroll
            for (int dt = 0; dt < 4; dt++) {
                int row = dt * 16 + lr;
                bf16x8 vf = *(const bf16x8*)(Vs + ((row * 128 + hk * 64 + lk * 16) ^ ((row & 7) << 4)));
                oacc[dt] = __builtin_amdgcn_mfma_f32_16x16x32_bf16(pf, vf, oacc[dt], 0, 0, 0);
            }
        }
        __syncthreads();   // done reading Ks/Vs/Ps before next stage
    }

    // ---- write attention output [B][T][D] ----
    int b = bh >> 4, h = bh & 15;
#pragma unroll
    for (int dt = 0; dt < 4; dt++) {
#pragma unroll
        for (int j = 0; j < 4; j++) {
            float ov = oacc[dt][j] / lsum[j];
            int t = q0 + wid * 16 + lk * 4 + j;
            Ao[((size_t)b * T_ + t) * D_ + h * DH_ + dt * 16 + lr] = (bf16_t)ov;
        }
    }
}

// ---------------- launch ----------------
extern "C" void kernel_launch(void* const* d_in, const int* in_sizes, int n_in,
                              void* d_out, int out_size, void* d_ws, size_t ws_size,
                              hipStream_t stream) {
    const float* x     = (const float*)d_in[0];
    const float* w_qkv = (const float*)d_in[1];
    const float* b_qkv = (const float*)d_in[2];
    const float* w_out = (const float*)d_in[3];
    const float* b_out = (const float*)d_in[4];
    float* out = (float*)d_out;

    char* ws = (char*)d_ws;
    bf16_t* xb    = (bf16_t*)(ws);               //  8 MB  [4096][1024]
    bf16_t* wqkvb = (bf16_t*)(ws + 8388608);     //  6 MB  [3072][1024]
    bf16_t* wob   = (bf16_t*)(ws + 14680064);    //  2 MB  [1024][1024]
    bf16_t* qb    = (bf16_t*)(ws + 16777216);    //  8 MB  [32][2048][64]
    bf16_t* kb    = (bf16_t*)(ws + 25165824);    //  8 MB  [32][2048][64]
    bf16_t* vtb   = (bf16_t*)(ws + 33554432);    //  8 MB  [32][64][2048]
    bf16_t* ab    = (bf16_t*)(ws + 41943040);    //  8 MB  [4096][1024]

    cvt_bf16<<<4096, 256, 0, stream>>>(x, xb, 4194304);
    cvt_bf16<<<3072, 256, 0, stream>>>(w_qkv, wqkvb, 3145728);
    cvt_bf16<<<1024, 256, 0, stream>>>(w_out, wob, 1048576);

    gemm128<0><<<dim3(24, 32), 256, 0, stream>>>(xb, wqkvb, b_qkv, qb, kb, vtb, nullptr, 1024, 3072);
    attn64<<<1024, 256, 0, stream>>>(qb, kb, vtb, ab);
    gemm128<1><<<dim3(8, 32), 256, 0, stream>>>(ab, wob, b_out, nullptr, nullptr, nullptr, out, 1024, 1024);
}

// Round 2
// 262.194 us; speedup vs baseline: 1.5565x; 1.5565x over previous
//
#include <hip/hip_runtime.h>
#include <hip/hip_bf16.h>
#include <math.h>

#define B_ 2
#define T_ 2048
#define D_ 1024
#define H_ 16
#define DH_ 64

typedef __bf16 bf16_t;
typedef bf16_t bf16x8 __attribute__((ext_vector_type(8)));
typedef bf16_t bf16x4 __attribute__((ext_vector_type(4)));
typedef float f32x4 __attribute__((ext_vector_type(4)));

typedef __attribute__((address_space(1))) const void gas_void;
typedef __attribute__((address_space(3))) void las_void;

__device__ __forceinline__ void gld16(const void* g, void* l) {
    __builtin_amdgcn_global_load_lds((gas_void*)g, (las_void*)l, 16, 0, 0);
}

// ---------------- fp32 -> bf16 convert ----------------
__global__ __launch_bounds__(256) void cvt_bf16(const float* __restrict__ in,
                                                bf16_t* __restrict__ out, int n) {
    int i = (blockIdx.x * 256 + threadIdx.x) * 4;
    if (i >= n) return;
    float4 f = *(const float4*)(in + i);
    bf16x4 v = { (bf16_t)f.x, (bf16_t)f.y, (bf16_t)f.z, (bf16_t)f.w };
    *(bf16x4*)(out + i) = v;
}

// ---------------- RoPE cos/sin table: [2048][32] float2 ----------------
__global__ __launch_bounds__(256) void rope_tab_k(float2* __restrict__ tab) {
    int i = blockIdx.x * 256 + threadIdx.x;   // 65536 entries
    int t = i >> 5, d2 = i & 31;
    float invf = exp2f(-(float)d2 * 0.4152410118609203f); // log2(1e4)/32
    float ang = (float)t * invf;
    float sn, cs;
    sincosf(ang, &sn, &cs);
    tab[i] = make_float2(cs, sn);
}

// ---------------- 128x128 GEMM, C = A @ B^T (+bias, + fused epilogue) ---------
// A: [M][K] bf16 row-major, Bw: [N][K] bf16 row-major.
// EPI=0: qkv -> RoPE(q,k) -> q[BH][T][64], k[BH][T][64], vT[BH][64][T]
//        (all stores via LDS-staged full 128B lines)
// EPI=1: fp32 store with bias
template<int EPI>
__global__ __launch_bounds__(256) void gemm128(const bf16_t* __restrict__ A,
                                               const bf16_t* __restrict__ Bw,
                                               const float* __restrict__ bias,
                                               const float2* __restrict__ tab,
                                               bf16_t* __restrict__ q_out,
                                               bf16_t* __restrict__ k_out,
                                               bf16_t* __restrict__ vt_out,
                                               float* __restrict__ f_out,
                                               int K, int N) {
    __shared__ char smem[32768];             // [0,8K)=As [8K,16K)=Bs; epilogue: 4x8KB wave tiles
    char* As = smem;
    char* Bs = smem + 8192;
    int tid = threadIdx.x;
    int lane = tid & 63, wid = tid >> 6;
    int wr = wid >> 1, wc = wid & 1;
    int lr = lane & 15, lk = lane >> 4;

    f32x4 acc[4][4];
    f32x4 z = {0.f, 0.f, 0.f, 0.f};
#pragma unroll
    for (int i = 0; i < 4; i++)
#pragma unroll
        for (int j = 0; j < 4; j++) acc[i][j] = z;

    const char* Ab = (const char*)(A + (size_t)blockIdx.y * 128 * K);
    const char* Bb = (const char*)(Bw + (size_t)blockIdx.x * 128 * K);
    const int rowstride = K * 2;

    for (int k0 = 0; k0 < K * 2; k0 += 64) {  // k0 in bytes (BK=32 elems)
#pragma unroll
        for (int c = 0; c < 2; c++) {
            int o = c * 4096 + tid * 16;      // byte offset inside 8KB tile
            int r = o >> 6, cb = o & 63;      // row, in-row byte
            gld16(Ab + (size_t)r * rowstride + k0 + cb, As + o);
            gld16(Bb + (size_t)r * rowstride + k0 + cb, Bs + o);
        }
        __syncthreads();
        bf16x8 af[4], bfr[4];
#pragma unroll
        for (int m = 0; m < 4; m++)
            af[m] = *(const bf16x8*)(As + (wr * 64 + m * 16 + lr) * 64 + lk * 16);
#pragma unroll
        for (int n = 0; n < 4; n++)
            bfr[n] = *(const bf16x8*)(Bs + (wc * 64 + n * 16 + lr) * 64 + lk * 16);
#pragma unroll
        for (int m = 0; m < 4; m++)
#pragma unroll
            for (int n = 0; n < 4; n++)
                acc[m][n] = __builtin_amdgcn_mfma_f32_16x16x32_bf16(af[m], bfr[n], acc[m][n], 0, 0, 0);
        __syncthreads();
    }
    // NOTE: final __syncthreads above makes smem safe to repurpose per-wave.

    // epilogue: C fragment layout col = lane&15, row = (lane>>4)*4 + j
    int m_base = blockIdx.y * 128 + wr * 64;
    int n_base = blockIdx.x * 128 + wc * 64;   // multiple of 64
    if (EPI == 1) {
#pragma unroll
        for (int m = 0; m < 4; m++) {
            int gm0 = m_base + m * 16 + lk * 4;
#pragma unroll
            for (int n = 0; n < 4; n++) {
                int nc = n_base + n * 16 + lr;
                float bv = bias[nc];
#pragma unroll
                for (int j = 0; j < 4; j++)
                    f_out[(size_t)(gm0 + j) * N + nc] = acc[m][n][j] + bv;
            }
        }
    } else {
        char* myL = smem + wid * 8192;          // wave-private [64][128B], XOR-swizzled
        int which = n_base >> 10;               // 0=q 1=k 2=v (uniform per wave)
        int h = (n_base & 1023) >> 6;
        int b = m_base >> 11, t0 = m_base & 2047;
        int bh = b * H_ + h;
        if (which == 2) {
            // stage C^T: row=dh(64), col=t(64)
#pragma unroll
            for (int m = 0; m < 4; m++)
#pragma unroll
                for (int n = 0; n < 4; n++) {
                    int rd = n * 16 + lr;
                    float bv = bias[n_base + rd];
#pragma unroll
                    for (int j = 0; j < 4; j++) {
                        int ct = m * 16 + lk * 4 + j;
                        int addr = (rd * 128 + ct * 2) ^ ((rd & 7) << 4);
                        *(bf16_t*)(myL + addr) = (bf16_t)(acc[m][n][j] + bv);
                    }
                }
#pragma unroll
            for (int it = 0; it < 8; it++) {
                int row = it * 8 + (lane >> 3);     // dh
                int byte = (lane & 7) * 16;
                bf16x8 val = *(const bf16x8*)(myL + ((row * 128 + byte) ^ ((row & 7) << 4)));
                *(bf16x8*)(vt_out + ((size_t)bh * DH_ + row) * T_ + t0 + (lane & 7) * 8) = val;
            }
        } else {
            bf16_t* dst = which ? k_out : q_out;
            // stage with RoPE: row=t(64), col=dh(64)
#pragma unroll
            for (int m = 0; m < 4; m++)
#pragma unroll
                for (int n = 0; n < 4; n++) {
                    int dh = n * 16 + lr;
                    float bv = bias[n_base + dh];
                    int dh2 = dh >> 1;
                    bool even = (dh & 1) == 0;
#pragma unroll
                    for (int j = 0; j < 4; j++) {
                        int rt = m * 16 + lk * 4 + j;
                        float v = acc[m][n][j] + bv;
                        float p = __shfl_xor(v, 1);   // partner dh^1 lives in lane^1
                        float2 cs = tab[(t0 + rt) * 32 + dh2];
                        float r = even ? v * cs.x - p * cs.y : v * cs.x + p * cs.y;
                        int addr = (rt * 128 + dh * 2) ^ ((rt & 7) << 4);
                        *(bf16_t*)(myL + addr) = (bf16_t)r;
                    }
                }
#pragma unroll
            for (int it = 0; it < 8; it++) {
                int row = it * 8 + (lane >> 3);     // t_local
                int byte = (lane & 7) * 16;
                bf16x8 val = *(const bf16x8*)(myL + ((row * 128 + byte) ^ ((row & 7) << 4)));
                *(bf16x8*)(dst + ((size_t)bh * T_ + t0 + row) * DH_ + (lane & 7) * 8) = val;
            }
        }
    }
}

// ---------------- flash attention: 1 block = (bh, 64 q rows), 4 waves ---------
__global__ __launch_bounds__(256) void attn64(const bf16_t* __restrict__ Q,
                                              const bf16_t* __restrict__ K,
                                              const bf16_t* __restrict__ Vt,
                                              bf16_t* __restrict__ Ao) {
    __shared__ char Ks[8192];      // [64 kv][64 dh] bf16, XOR-swizzled
    __shared__ char Vs[8192];      // [64 d][64 kv]  bf16, XOR-swizzled
    __shared__ char Ps[4][2048];   // per-wave P [16 q][64 kv] bf16, swizzled

    int tid = threadIdx.x;
    int lane = tid & 63, wid = tid >> 6;
    int lr = lane & 15, lk = lane >> 4;
    int bh = blockIdx.x >> 5, qt = blockIdx.x & 31;
    int q0 = qt * 64;

    const bf16_t* Qp = Q + ((size_t)bh * T_ + q0 + wid * 16 + lr) * DH_;
    bf16x8 qf0 = *(const bf16x8*)(Qp + lk * 8);
    bf16x8 qf1 = *(const bf16x8*)(Qp + 32 + lk * 8);

    f32x4 zz = {0.f, 0.f, 0.f, 0.f};
    f32x4 oacc[4];
#pragma unroll
    for (int dt = 0; dt < 4; dt++) oacc[dt] = zz;
    float mrun[4], lsum[4];
    int qrow[4];
#pragma unroll
    for (int j = 0; j < 4; j++) {
        mrun[j] = -__builtin_inff();
        lsum[j] = 0.f;
        qrow[j] = q0 + wid * 16 + lk * 4 + j;
    }

    const char* Kbase = (const char*)(K + (size_t)bh * T_ * DH_);
    const char* Vbase = (const char*)(Vt + (size_t)bh * DH_ * T_);
    const float LOG2E = 1.44269504088896f;

    for (int s = 0; s <= qt; ++s) {
        int kv0 = s * 64;
        const char* Kg = Kbase + (size_t)kv0 * (DH_ * 2);
#pragma unroll
        for (int c = 0; c < 2; c++) {
            int o = c * 4096 + tid * 16;
            int r = o >> 7;                       // tile row (128B rows)
            int g = o ^ ((r & 7) << 4);           // pre-swizzled source (involution)
            gld16(Kg + g, Ks + o);                // K tile is contiguous 8KB
            gld16(Vbase + (size_t)r * (T_ * 2) + kv0 * 2 + (g & 127), Vs + o);
        }
        __syncthreads();

        // ---- QK^T (S rows=q, cols=kv), mask, scale ----
        float sf[4][4];
#pragma unroll
        for (int kt = 0; kt < 4; kt++) {
            f32x4 sacc = zz;
            int row = kt * 16 + lr;
            int key = (row & 7) << 4;
            bf16x8 kf0 = *(const bf16x8*)(Ks + ((row * 128 + lk * 16) ^ key));
            bf16x8 kf1 = *(const bf16x8*)(Ks + ((row * 128 + 64 + lk * 16) ^ key));
            sacc = __builtin_amdgcn_mfma_f32_16x16x32_bf16(qf0, kf0, sacc, 0, 0, 0);
            sacc = __builtin_amdgcn_mfma_f32_16x16x32_bf16(qf1, kf1, sacc, 0, 0, 0);
            int kvc = kv0 + kt * 16 + lr;
#pragma unroll
            for (int j = 0; j < 4; j++) {
                float sv = sacc[j] * 0.125f;  // 1/sqrt(64)
                sf[kt][j] = (kvc <= qrow[j]) ? sv : -__builtin_inff();
            }
        }

        // ---- online softmax ----
        float mnew[4], fac[4], rs[4];
#pragma unroll
        for (int j = 0; j < 4; j++) {
            float mx = fmaxf(fmaxf(sf[0][j], sf[1][j]), fmaxf(sf[2][j], sf[3][j]));
#pragma unroll
            for (int dd = 1; dd < 16; dd <<= 1) mx = fmaxf(mx, __shfl_xor(mx, dd));
            mnew[j] = fmaxf(mrun[j], mx);
            fac[j] = exp2f((mrun[j] - mnew[j]) * LOG2E);
            mrun[j] = mnew[j];
            rs[j] = 0.f;
        }
        f32x4 facv = { fac[0], fac[1], fac[2], fac[3] };
#pragma unroll
        for (int dt = 0; dt < 4; dt++) oacc[dt] *= facv;
#pragma unroll
        for (int kt = 0; kt < 4; kt++) {
#pragma unroll
            for (int j = 0; j < 4; j++) {
                float p = exp2f((sf[kt][j] - mnew[j]) * LOG2E);
                rs[j] += p;
                int prow = lk * 4 + j;
                int addr = (prow * 128 + (kt * 16 + lr) * 2) ^ ((prow & 7) << 4);
                *(bf16_t*)(&Ps[wid][addr]) = (bf16_t)p;
            }
        }
#pragma unroll
        for (int j = 0; j < 4; j++) {
#pragma unroll
            for (int dd = 1; dd < 16; dd <<= 1) rs[j] += __shfl_xor(rs[j], dd);
            lsum[j] = lsum[j] * fac[j] + rs[j];
        }
        __syncthreads();   // P visible; QK reads of Ks done

        // ---- PV:  O += P @ V  (Vt rows are d, so B-frag is contiguous) ----
#pragma unroll
        for (int hk = 0; hk < 2; hk++) {
            bf16x8 pf = *(const bf16x8*)(&Ps[wid][(lr * 128 + hk * 64 + lk * 16) ^ ((lr & 7) << 4)]);
#pragma unroll
            for (int dt = 0; dt < 4; dt++) {
                int row = dt * 16 + lr;
                bf16x8 vf = *(const bf16x8*)(Vs + ((row * 128 + hk * 64 + lk * 16) ^ ((row & 7) << 4)));
                oacc[dt] = __builtin_amdgcn_mfma_f32_16x16x32_bf16(pf, vf, oacc[dt], 0, 0, 0);
            }
        }
        __syncthreads();   // done reading Ks/Vs/Ps before next stage
    }

    // ---- write attention output [B][T][D] via LDS-staged 128B rows ----
    int b = bh >> 4, h = bh & 15;
#pragma unroll
    for (int dt = 0; dt < 4; dt++)
#pragma unroll
        for (int j = 0; j < 4; j++) {
            int row = lk * 4 + j;
            int col = dt * 16 + lr;
            int addr = (row * 128 + col * 2) ^ ((row & 7) << 4);
            *(bf16_t*)(&Ps[wid][addr]) = (bf16_t)(oacc[dt][j] / lsum[j]);
        }
#pragma unroll
    for (int it = 0; it < 2; it++) {
        int row = it * 8 + (lane >> 3);
        int byte = (lane & 7) * 16;
        bf16x8 val = *(const bf16x8*)(&Ps[wid][(row * 128 + byte) ^ ((row & 7) << 4)]);
        int t = q0 + wid * 16 + row;
        *(bf16x8*)(Ao + ((size_t)b * T_ + t) * D_ + h * DH_ + (lane & 7) * 8) = val;
    }
}

// ---------------- launch ----------------
extern "C" void kernel_launch(void* const* d_in, const int* in_sizes, int n_in,
                              void* d_out, int out_size, void* d_ws, size_t ws_size,
                              hipStream_t stream) {
    const float* x     = (const float*)d_in[0];
    const float* w_qkv = (const float*)d_in[1];
    const float* b_qkv = (const float*)d_in[2];
    const float* w_out = (const float*)d_in[3];
    const float* b_out = (const float*)d_in[4];
    float* out = (float*)d_out;

    char* ws = (char*)d_ws;
    bf16_t* xb    = (bf16_t*)(ws);               //  8 MB  [4096][1024]
    bf16_t* wqkvb = (bf16_t*)(ws + 8388608);     //  6 MB  [3072][1024]
    bf16_t* wob   = (bf16_t*)(ws + 14680064);    //  2 MB  [1024][1024]
    bf16_t* qb    = (bf16_t*)(ws + 16777216);    //  8 MB  [32][2048][64]
    bf16_t* kb    = (bf16_t*)(ws + 25165824);    //  8 MB  [32][2048][64]
    bf16_t* vtb   = (bf16_t*)(ws + 33554432);    //  8 MB  [32][64][2048]
    bf16_t* ab    = (bf16_t*)(ws + 41943040);    //  8 MB  [4096][1024]
    float2* tab   = (float2*)(ws + 41943040);    // 512 KB RoPE table, lives in ab region
                                                 // (consumed by gemm<0>, overwritten later by attn)

    rope_tab_k<<<256, 256, 0, stream>>>(tab);
    cvt_bf16<<<4096, 256, 0, stream>>>(x, xb, 4194304);
    cvt_bf16<<<3072, 256, 0, stream>>>(w_qkv, wqkvb, 3145728);
    cvt_bf16<<<1024, 256, 0, stream>>>(w_out, wob, 1048576);

    gemm128<0><<<dim3(24, 32), 256, 0, stream>>>(xb, wqkvb, b_qkv, tab, qb, kb, vtb, nullptr, 1024, 3072);
    attn64<<<1024, 256, 0, stream>>>(qb, kb, vtb, ab);
    gemm128<1><<<dim3(8, 32), 256, 0, stream>>>(ab, wob, b_out, nullptr, nullptr, nullptr, nullptr, out, 1024, 1024);
}

// Round 3
// 158.137 us; speedup vs baseline: 2.5808x; 1.6580x over previous
//
#include <hip/hip_runtime.h>
#include <hip/hip_bf16.h>
#include <math.h>

#define B_ 2
#define T_ 2048
#define D_ 1024
#define H_ 16
#define DH_ 64

typedef __bf16 bf16_t;
typedef bf16_t bf16x8 __attribute__((ext_vector_type(8)));
typedef bf16_t bf16x4 __attribute__((ext_vector_type(4)));
typedef float f32x4 __attribute__((ext_vector_type(4)));

typedef __attribute__((address_space(1))) const void gas_void;
typedef __attribute__((address_space(3))) void las_void;

__device__ __forceinline__ void gld16(const void* g, void* l) {
    __builtin_amdgcn_global_load_lds((gas_void*)g, (las_void*)l, 16, 0, 0);
}

// ---------------- fp32 -> bf16 convert ----------------
__global__ __launch_bounds__(256) void cvt_bf16(const float* __restrict__ in,
                                                bf16_t* __restrict__ out, int n) {
    int i = (blockIdx.x * 256 + threadIdx.x) * 4;
    if (i >= n) return;
    float4 f = *(const float4*)(in + i);
    bf16x4 v = { (bf16_t)f.x, (bf16_t)f.y, (bf16_t)f.z, (bf16_t)f.w };
    *(bf16x4*)(out + i) = v;
}

// ---------------- RoPE cos/sin table: [2048][32] float2 ----------------
__global__ __launch_bounds__(256) void rope_tab_k(float2* __restrict__ tab) {
    int i = blockIdx.x * 256 + threadIdx.x;   // 65536 entries
    int t = i >> 5, d2 = i & 31;
    float invf = exp2f(-(float)d2 * 0.4152410118609203f); // log2(1e4)/32
    float ang = (float)t * invf;
    float sn, cs;
    sincosf(ang, &sn, &cs);
    tab[i] = make_float2(cs, sn);
}

// ---------------- 128x128 GEMM, C = A @ B^T (+bias, + fused epilogue) ---------
// EPI=0: qkv -> RoPE(q,k) -> q[BH][T][64], k[BH][T][64], vT[BH][64][T]
//        vT t-coordinate is sigma^-1-permuted within 32-blocks so attention's
//        PV B-fragment (P kept in registers, lane-local) matches V's k-slots.
// EPI=1: fp32 store with bias
template<int EPI>
__global__ __launch_bounds__(256) void gemm128(const bf16_t* __restrict__ A,
                                               const bf16_t* __restrict__ Bw,
                                               const float* __restrict__ bias,
                                               const float2* __restrict__ tab,
                                               bf16_t* __restrict__ q_out,
                                               bf16_t* __restrict__ k_out,
                                               bf16_t* __restrict__ vt_out,
                                               float* __restrict__ f_out,
                                               int K, int N) {
    __shared__ char smem[32768];             // [0,8K)=As [8K,16K)=Bs; epilogue: 4x8KB wave tiles
    char* As = smem;
    char* Bs = smem + 8192;
    int tid = threadIdx.x;
    int lane = tid & 63, wid = tid >> 6;
    int wr = wid >> 1, wc = wid & 1;
    int lr = lane & 15, lk = lane >> 4;

    f32x4 acc[4][4];
    f32x4 z = {0.f, 0.f, 0.f, 0.f};
#pragma unroll
    for (int i = 0; i < 4; i++)
#pragma unroll
        for (int j = 0; j < 4; j++) acc[i][j] = z;

    const char* Ab = (const char*)(A + (size_t)blockIdx.y * 128 * K);
    const char* Bb = (const char*)(Bw + (size_t)blockIdx.x * 128 * K);
    const int rowstride = K * 2;

    for (int k0 = 0; k0 < K * 2; k0 += 64) {  // k0 in bytes (BK=32 elems)
#pragma unroll
        for (int c = 0; c < 2; c++) {
            int o = c * 4096 + tid * 16;      // byte offset inside 8KB tile
            int r = o >> 6, cb = o & 63;      // row, in-row byte
            gld16(Ab + (size_t)r * rowstride + k0 + cb, As + o);
            gld16(Bb + (size_t)r * rowstride + k0 + cb, Bs + o);
        }
        __syncthreads();
        bf16x8 af[4], bfr[4];
#pragma unroll
        for (int m = 0; m < 4; m++)
            af[m] = *(const bf16x8*)(As + (wr * 64 + m * 16 + lr) * 64 + lk * 16);
#pragma unroll
        for (int n = 0; n < 4; n++)
            bfr[n] = *(const bf16x8*)(Bs + (wc * 64 + n * 16 + lr) * 64 + lk * 16);
#pragma unroll
        for (int m = 0; m < 4; m++)
#pragma unroll
            for (int n = 0; n < 4; n++)
                acc[m][n] = __builtin_amdgcn_mfma_f32_16x16x32_bf16(af[m], bfr[n], acc[m][n], 0, 0, 0);
        __syncthreads();
    }

    // epilogue: C fragment layout col = lane&15, row = (lane>>4)*4 + j
    int m_base = blockIdx.y * 128 + wr * 64;
    int n_base = blockIdx.x * 128 + wc * 64;   // multiple of 64
    if (EPI == 1) {
#pragma unroll
        for (int m = 0; m < 4; m++) {
            int gm0 = m_base + m * 16 + lk * 4;
#pragma unroll
            for (int n = 0; n < 4; n++) {
                int nc = n_base + n * 16 + lr;
                float bv = bias[nc];
#pragma unroll
                for (int j = 0; j < 4; j++)
                    f_out[(size_t)(gm0 + j) * N + nc] = acc[m][n][j] + bv;
            }
        }
    } else {
        char* myL = smem + wid * 8192;          // wave-private [64][128B], XOR-swizzled
        int which = n_base >> 10;               // 0=q 1=k 2=v (uniform per wave)
        int h = (n_base & 1023) >> 6;
        int b = m_base >> 11, t0 = m_base & 2047;
        int bh = b * H_ + h;
        if (which == 2) {
            // stage C^T: row=dh(64), col=t(64), t sigma^-1-permuted in 32-blocks
#pragma unroll
            for (int m = 0; m < 4; m++)
#pragma unroll
                for (int n = 0; n < 4; n++) {
                    int rd = n * 16 + lr;
                    float bv = bias[n_base + rd];
#pragma unroll
                    for (int j = 0; j < 4; j++) {
                        int ct = m * 16 + lk * 4 + j;
                        int ct2 = (ct & 32) | (((ct >> 2) & 3) << 3) | (((ct >> 4) & 1) << 2) | (ct & 3);
                        int addr = (rd * 128 + ct2 * 2) ^ ((rd & 7) << 4);
                        *(bf16_t*)(myL + addr) = (bf16_t)(acc[m][n][j] + bv);
                    }
                }
#pragma unroll
            for (int it = 0; it < 8; it++) {
                int row = it * 8 + (lane >> 3);     // dh
                int byte = (lane & 7) * 16;
                bf16x8 val = *(const bf16x8*)(myL + ((row * 128 + byte) ^ ((row & 7) << 4)));
                *(bf16x8*)(vt_out + ((size_t)bh * DH_ + row) * T_ + t0 + (lane & 7) * 8) = val;
            }
        } else {
            bf16_t* dst = which ? k_out : q_out;
            // stage with RoPE: row=t(64), col=dh(64)
#pragma unroll
            for (int m = 0; m < 4; m++)
#pragma unroll
                for (int n = 0; n < 4; n++) {
                    int dh = n * 16 + lr;
                    float bv = bias[n_base + dh];
                    int dh2 = dh >> 1;
                    bool even = (dh & 1) == 0;
#pragma unroll
                    for (int j = 0; j < 4; j++) {
                        int rt = m * 16 + lk * 4 + j;
                        float v = acc[m][n][j] + bv;
                        float p = __shfl_xor(v, 1);   // partner dh^1 lives in lane^1
                        float2 cs = tab[(t0 + rt) * 32 + dh2];
                        float r = even ? v * cs.x - p * cs.y : v * cs.x + p * cs.y;
                        int addr = (rt * 128 + dh * 2) ^ ((rt & 7) << 4);
                        *(bf16_t*)(myL + addr) = (bf16_t)r;
                    }
                }
#pragma unroll
            for (int it = 0; it < 8; it++) {
                int row = it * 8 + (lane >> 3);     // t_local
                int byte = (lane & 7) * 16;
                bf16x8 val = *(const bf16x8*)(myL + ((row * 128 + byte) ^ ((row & 7) << 4)));
                *(bf16x8*)(dst + ((size_t)bh * T_ + t0 + row) * DH_ + (lane & 7) * 8) = val;
            }
        }
    }
}

// ---------------- flash attention, S^T formulation, register softmax ----------
// block = (bh, 64 q rows), 4 waves x 16 q-rows. K/V double-buffered, 1 barrier/step.
__global__ __launch_bounds__(256) void attn64(const bf16_t* __restrict__ Q,
                                              const bf16_t* __restrict__ K,
                                              const bf16_t* __restrict__ Vt,
                                              bf16_t* __restrict__ Ao) {
    __shared__ char smem[32768];   // Ks[2] @0,8K ; Vs[2] @16K,24K

    int tid = threadIdx.x;
    int lane = tid & 63, wid = tid >> 6;
    int lr = lane & 15, lk = lane >> 4;
    int bh = blockIdx.x & 31, qt = blockIdx.x >> 5;   // decorrelate qt from CU
    int q0 = qt * 64;
    int qrel = wid * 16 + lr;                          // q row within block

    const bf16_t* Qp = Q + ((size_t)bh * T_ + q0 + qrel) * DH_;
    bf16x8 qf0 = *(const bf16x8*)(Qp + lk * 8);
    bf16x8 qf1 = *(const bf16x8*)(Qp + 32 + lk * 8);

    f32x4 zz = {0.f, 0.f, 0.f, 0.f};
    f32x4 oacc[4];                                     // O^T: col q=lr, rows dh
#pragma unroll
    for (int dt = 0; dt < 4; dt++) oacc[dt] = zz;
    float mrun = -__builtin_inff(), lsum = 0.f;

    const char* Kbase = (const char*)(K + (size_t)bh * T_ * DH_);
    const char* Vbase = (const char*)(Vt + (size_t)bh * DH_ * T_);
    const float SCL2 = 0.18033688011112042f;           // (1/8) * log2(e)

    auto stage = [&](int s, char* Kd, char* Vd) {
        int kv0 = s * 64;
        const char* Kg = Kbase + (size_t)kv0 * 128;
#pragma unroll
        for (int c = 0; c < 2; c++) {
            int o = c * 4096 + tid * 16;
            int r = o >> 7;
            int g = o ^ ((r & 7) << 4);               // pre-swizzled source (involution)
            gld16(Kg + g, Kd + o);
            gld16(Vbase + (size_t)r * (T_ * 2) + kv0 * 2 + (g & 127), Vd + o);
        }
    };

    auto compute = [&](const char* Kc, const char* Vc, bool dmask) __attribute__((always_inline)) {
        // ---- QK^T -> S^T: col q=lr, row kv = kt*16 + lk*4 + j ----
        float p[4][4];
#pragma unroll
        for (int kt = 0; kt < 4; kt++) {
            int row = kt * 16 + lr;
            int key = (row & 7) << 4;
            bf16x8 kf0 = *(const bf16x8*)(Kc + ((row * 128 + lk * 16) ^ key));
            bf16x8 kf1 = *(const bf16x8*)(Kc + ((row * 128 + 64 + lk * 16) ^ key));
            f32x4 sacc = zz;
            sacc = __builtin_amdgcn_mfma_f32_16x16x32_bf16(kf0, qf0, sacc, 0, 0, 0);
            sacc = __builtin_amdgcn_mfma_f32_16x16x32_bf16(kf1, qf1, sacc, 0, 0, 0);
#pragma unroll
            for (int j = 0; j < 4; j++) {
                float sv = sacc[j] * SCL2;             // base-2 domain
                if (dmask) {
                    int kvrel = kt * 16 + lk * 4 + j;
                    sv = (kvrel <= qrel) ? sv : -__builtin_inff();
                }
                p[kt][j] = sv;
            }
        }
        // ---- online softmax (per-lane: one q row) ----
        float mx = p[0][0];
#pragma unroll
        for (int kt = 0; kt < 4; kt++)
#pragma unroll
            for (int j = 0; j < 4; j++) mx = fmaxf(mx, p[kt][j]);
        mx = fmaxf(mx, __shfl_xor(mx, 16));
        mx = fmaxf(mx, __shfl_xor(mx, 32));
        float mnew = fmaxf(mrun, mx);
        float fac = exp2f(mrun - mnew);
        mrun = mnew;
        float rs = 0.f;
#pragma unroll
        for (int kt = 0; kt < 4; kt++)
#pragma unroll
            for (int j = 0; j < 4; j++) {
                float e = exp2f(p[kt][j] - mnew);
                p[kt][j] = e;
                rs += e;
            }
        rs += __shfl_xor(rs, 16);
        rs += __shfl_xor(rs, 32);
        lsum = lsum * fac + rs;
        // ---- pack P^T B-fragments in-lane (k-slot order matches sigma'd V) ----
        bf16x8 pb0 = { (bf16_t)p[0][0], (bf16_t)p[0][1], (bf16_t)p[0][2], (bf16_t)p[0][3],
                       (bf16_t)p[1][0], (bf16_t)p[1][1], (bf16_t)p[1][2], (bf16_t)p[1][3] };
        bf16x8 pb1 = { (bf16_t)p[2][0], (bf16_t)p[2][1], (bf16_t)p[2][2], (bf16_t)p[2][3],
                       (bf16_t)p[3][0], (bf16_t)p[3][1], (bf16_t)p[3][2], (bf16_t)p[3][3] };
        // ---- rescale O, then PV: O^T += V^T . P ----
#pragma unroll
        for (int dt = 0; dt < 4; dt++) {
            f32x4 o = oacc[dt];
            o[0] *= fac; o[1] *= fac; o[2] *= fac; o[3] *= fac;
            int row = dt * 16 + lr;
            int key = (row & 7) << 4;
            bf16x8 vf0 = *(const bf16x8*)(Vc + ((row * 128 + lk * 16) ^ key));
            bf16x8 vf1 = *(const bf16x8*)(Vc + ((row * 128 + 64 + lk * 16) ^ key));
            o = __builtin_amdgcn_mfma_f32_16x16x32_bf16(vf0, pb0, o, 0, 0, 0);
            o = __builtin_amdgcn_mfma_f32_16x16x32_bf16(vf1, pb1, o, 0, 0, 0);
            oacc[dt] = o;
        }
    };

    stage(0, smem, smem + 16384);
    __syncthreads();
    for (int s = 0; s < qt; ++s) {
        char* Kc = smem + ((s & 1) ? 8192 : 0);
        char* Vc = smem + 16384 + ((s & 1) ? 8192 : 0);
        char* Kn = smem + ((s & 1) ? 0 : 8192);
        char* Vn = smem + 16384 + ((s & 1) ? 0 : 8192);
        stage(s + 1, Kn, Vn);                 // in flight across compute
        compute(Kc, Vc, false);
        __syncthreads();                      // drains prefetch, releases bufs
    }
    {   // diagonal step with causal mask
        char* Kc = smem + ((qt & 1) ? 8192 : 0);
        char* Vc = smem + 16384 + ((qt & 1) ? 8192 : 0);
        compute(Kc, Vc, true);
    }
    __syncthreads();                          // all reads done before restaging

    // ---- write O: stage per-wave [16 q][64 dh] then 128B-row stores ----
    char* myL = smem + wid * 2048;
    float rinv = __builtin_amdgcn_rcpf(lsum);
#pragma unroll
    for (int dt = 0; dt < 4; dt++)
#pragma unroll
        for (int j = 0; j < 4; j++) {
            int dh = dt * 16 + lk * 4 + j;
            int addr = (lr * 128 + dh * 2) ^ ((lr & 7) << 4);
            *(bf16_t*)(myL + addr) = (bf16_t)(oacc[dt][j] * rinv);
        }
    int b = bh >> 4, h = bh & 15;
#pragma unroll
    for (int it = 0; it < 2; it++) {
        int row = it * 8 + (lane >> 3);
        int byte = (lane & 7) * 16;
        bf16x8 val = *(const bf16x8*)(myL + ((row * 128 + byte) ^ ((row & 7) << 4)));
        int t = q0 + wid * 16 + row;
        *(bf16x8*)(Ao + ((size_t)b * T_ + t) * D_ + h * DH_ + (lane & 7) * 8) = val;
    }
}

// ---------------- launch ----------------
extern "C" void kernel_launch(void* const* d_in, const int* in_sizes, int n_in,
                              void* d_out, int out_size, void* d_ws, size_t ws_size,
                              hipStream_t stream) {
    const float* x     = (const float*)d_in[0];
    const float* w_qkv = (const float*)d_in[1];
    const float* b_qkv = (const float*)d_in[2];
    const float* w_out = (const float*)d_in[3];
    const float* b_out = (const float*)d_in[4];
    float* out = (float*)d_out;

    char* ws = (char*)d_ws;
    bf16_t* xb    = (bf16_t*)(ws);               //  8 MB  [4096][1024]
    bf16_t* wqkvb = (bf16_t*)(ws + 8388608);     //  6 MB  [3072][1024]
    bf16_t* wob   = (bf16_t*)(ws + 14680064);    //  2 MB  [1024][1024]
    bf16_t* qb    = (bf16_t*)(ws + 16777216);    //  8 MB  [32][2048][64]
    bf16_t* kb    = (bf16_t*)(ws + 25165824);    //  8 MB  [32][2048][64]
    bf16_t* vtb   = (bf16_t*)(ws + 33554432);    //  8 MB  [32][64][2048] (sigma-permuted t)
    bf16_t* ab    = (bf16_t*)(ws + 41943040);    //  8 MB  [4096][1024]
    float2* tab   = (float2*)(ws + 41943040);    // 512 KB RoPE table, lives in ab region

    rope_tab_k<<<256, 256, 0, stream>>>(tab);
    cvt_bf16<<<4096, 256, 0, stream>>>(x, xb, 4194304);
    cvt_bf16<<<3072, 256, 0, stream>>>(w_qkv, wqkvb, 3145728);
    cvt_bf16<<<1024, 256, 0, stream>>>(w_out, wob, 1048576);

    gemm128<0><<<dim3(24, 32), 256, 0, stream>>>(xb, wqkvb, b_qkv, tab, qb, kb, vtb, nullptr, 1024, 3072);
    attn64<<<1024, 256, 0, stream>>>(qb, kb, vtb, ab);
    gemm128<1><<<dim3(8, 32), 256, 0, stream>>>(ab, wob, b_out, nullptr, nullptr, nullptr, nullptr, out, 1024, 1024);
}

// Round 4
// 125.972 us; speedup vs baseline: 3.2397x; 1.2553x over previous
//
#include <hip/hip_runtime.h>
#include <hip/hip_bf16.h>
#include <math.h>
#include <type_traits>

#define B_ 2
#define T_ 2048
#define D_ 1024
#define H_ 16
#define DH_ 64

typedef __bf16 bf16_t;
typedef bf16_t bf16x8 __attribute__((ext_vector_type(8)));
typedef bf16_t bf16x4 __attribute__((ext_vector_type(4)));
typedef float f32x4 __attribute__((ext_vector_type(4)));

typedef __attribute__((address_space(1))) const void gas_void;
typedef __attribute__((address_space(3))) void las_void;

__device__ __forceinline__ void gld16(const void* g, void* l) {
    __builtin_amdgcn_global_load_lds((gas_void*)g, (las_void*)l, 16, 0, 0);
}

// ---------------- fused fp32 -> bf16 convert (x, w_qkv, w_out) ----------------
__global__ __launch_bounds__(256) void cvt3(const float* __restrict__ a,   // 4194304
                                            const float* __restrict__ b,   // 3145728
                                            const float* __restrict__ c,   // 1048576
                                            bf16_t* __restrict__ oa,
                                            bf16_t* __restrict__ ob,
                                            bf16_t* __restrict__ oc) {
    int i = blockIdx.x * 256 + threadIdx.x;          // vec4 index, 2097152 total
    const float* src; bf16_t* dst; int off;
    if (i < 1048576)      { src = a; dst = oa; off = i; }
    else if (i < 1835008) { src = b; dst = ob; off = i - 1048576; }
    else                  { src = c; dst = oc; off = i - 1835008; }
    float4 f = ((const float4*)src)[off];
    bf16x4 v = { (bf16_t)f.x, (bf16_t)f.y, (bf16_t)f.z, (bf16_t)f.w };
    ((bf16x4*)dst)[off] = v;
}

// ---------------- RoPE cos/sin table: [2048][32] float2 ----------------
__global__ __launch_bounds__(256) void rope_tab_k(float2* __restrict__ tab) {
    int i = blockIdx.x * 256 + threadIdx.x;   // 65536 entries
    int t = i >> 5, d2 = i & 31;
    float invf = exp2f(-(float)d2 * 0.4152410118609203f); // log2(1e4)/32
    float ang = (float)t * invf;
    float sn, cs;
    sincosf(ang, &sn, &cs);
    tab[i] = make_float2(cs, sn);
}

// ---------------- 128x128 GEMM, C = A @ B^T, 3-deep counted-vmcnt pipeline ----
// K must be 1024 (32 steps of BK=32). LDS: 3 x (A 8KB + B 8KB) = 48KB.
// EPI=0: qkv -> RoPE(q,k) -> q[BH][T][64], k[BH][T][64], vT[BH][64][T] (sigma'd t)
// EPI=1: fp32 store with bias
template<int EPI>
__global__ __launch_bounds__(256) void gemm128(const bf16_t* __restrict__ A,
                                               const bf16_t* __restrict__ Bw,
                                               const float* __restrict__ bias,
                                               const float2* __restrict__ tab,
                                               bf16_t* __restrict__ q_out,
                                               bf16_t* __restrict__ k_out,
                                               bf16_t* __restrict__ vt_out,
                                               float* __restrict__ f_out,
                                               int K, int N) {
    __shared__ __align__(16) char smem[49152];
    char* b0 = smem;
    char* b1 = smem + 16384;
    char* b2 = smem + 32768;

    int tid = threadIdx.x;
    int lane = tid & 63, wid = tid >> 6;
    int wr = wid >> 1, wc = wid & 1;
    int lr = lane & 15, lk = lane >> 4;

    // ---- T1: bijective XCD chunking (nwg % 8 == 0) ----
    int l = blockIdx.y * gridDim.x + blockIdx.x;
    int chunk = (gridDim.x * gridDim.y) >> 3;
    int u = (l & 7) * chunk + (l >> 3);
    int bx = u % gridDim.x;
    int by = u / gridDim.x;

    f32x4 acc[4][4];
    f32x4 z = {0.f, 0.f, 0.f, 0.f};
#pragma unroll
    for (int i = 0; i < 4; i++)
#pragma unroll
        for (int j = 0; j < 4; j++) acc[i][j] = z;

    const char* Ab = (const char*)(A + (size_t)by * 128 * K);
    const char* Bb = (const char*)(Bw + (size_t)bx * 128 * K);
    const int rowstride = K * 2;

    // ---- per-thread staging addresses (T2 swizzle baked into global src) ----
    int p0 = tid * 16;                 // physical LDS byte (c=0)
    int p1 = 4096 + tid * 16;          // c=1
    int r0 = p0 >> 6, r1 = p1 >> 6;
    int cb0 = (p0 & 63) ^ (((r0 >> 1) & 3) << 4);
    int cb1 = (p1 & 63) ^ (((r1 >> 1) & 3) << 4);
    size_t gA0 = (size_t)r0 * rowstride + cb0;
    size_t gA1 = (size_t)r1 * rowstride + cb1;

    // ---- fragment read offsets (same swizzle) ----
    int oa[4], ob[4];
#pragma unroll
    for (int m = 0; m < 4; m++) {
        int row = wr * 64 + m * 16 + lr;
        oa[m] = row * 64 + ((lk * 16) ^ (((row >> 1) & 3) << 4));
    }
#pragma unroll
    for (int n = 0; n < 4; n++) {
        int row = wc * 64 + n * 16 + lr;
        ob[n] = row * 64 + ((lk * 16) ^ (((row >> 1) & 3) << 4));
    }

    auto stg = [&](char* buf, int ks) __attribute__((always_inline)) {
        const char* Ag = Ab + (size_t)ks * 64;
        const char* Bg = Bb + (size_t)ks * 64;
        gld16(Ag + gA0, buf + p0);
        gld16(Ag + gA1, buf + p1);
        gld16(Bg + gA0, buf + 8192 + p0);
        gld16(Bg + gA1, buf + 8192 + p1);
    };

    auto iterf = [&](auto vmc, char* buf, int ks, bool dostage) __attribute__((always_inline)) {
        constexpr int VM = decltype(vmc)::value;
        if constexpr (VM == 8)      asm volatile("s_waitcnt vmcnt(8)" ::: "memory");
        else if constexpr (VM == 4) asm volatile("s_waitcnt vmcnt(4)" ::: "memory");
        else                        asm volatile("s_waitcnt vmcnt(0)" ::: "memory");
        __builtin_amdgcn_s_barrier();
        asm volatile("" ::: "memory");
        bf16x8 Af[4], Bf[4];
#pragma unroll
        for (int m = 0; m < 4; m++) Af[m] = *(const bf16x8*)(buf + oa[m]);
#pragma unroll
        for (int n = 0; n < 4; n++) Bf[n] = *(const bf16x8*)(buf + 8192 + ob[n]);
#pragma unroll
        for (int m = 0; m < 4; m++)
#pragma unroll
            for (int n = 0; n < 4; n++)
                acc[m][n] = __builtin_amdgcn_mfma_f32_16x16x32_bf16(Af[m], Bf[n], acc[m][n], 0, 0, 0);
        asm volatile("" ::: "memory");
        __builtin_amdgcn_s_barrier();
        asm volatile("" ::: "memory");
        if (dostage) stg(buf, ks);
    };

    std::integral_constant<int, 8> c8;
    std::integral_constant<int, 4> c4;
    std::integral_constant<int, 0> c0;

    // prologue: stages 0,1,2 in flight
    stg(b0, 0);
    stg(b1, 1);
    stg(b2, 2);
    // steady state: iter u computes stage u, issues stage u+3 into same buffer
    for (int s = 0; s < 30; s += 3) {
        iterf(c8, b0, s + 3, s + 3 < 32);
        iterf(c8, b1, s + 4, s + 4 < 32);
        iterf(c8, b2, s + 5, s + 5 < 32);
    }
    iterf(c4, b0, 0, false);   // u=30
    iterf(c0, b1, 0, false);   // u=31  (drains everything)

    // epilogue: C fragment layout col = lane&15, row = (lane>>4)*4 + j
    int m_base = by * 128 + wr * 64;
    int n_base = bx * 128 + wc * 64;   // multiple of 64
    if (EPI == 1) {
#pragma unroll
        for (int m = 0; m < 4; m++) {
            int gm0 = m_base + m * 16 + lk * 4;
#pragma unroll
            for (int n = 0; n < 4; n++) {
                int nc = n_base + n * 16 + lr;
                float bv = bias[nc];
#pragma unroll
                for (int j = 0; j < 4; j++)
                    f_out[(size_t)(gm0 + j) * N + nc] = acc[m][n][j] + bv;
            }
        }
    } else {
        char* myL = smem + wid * 8192;          // wave-private [64][128B], XOR-swizzled
        int which = n_base >> 10;               // 0=q 1=k 2=v (uniform per wave)
        int h = (n_base & 1023) >> 6;
        int b = m_base >> 11, t0 = m_base & 2047;
        int bh = b * H_ + h;
        if (which == 2) {
            // stage C^T: row=dh(64), col=t(64), t sigma^-1-permuted in 32-blocks
#pragma unroll
            for (int m = 0; m < 4; m++)
#pragma unroll
                for (int n = 0; n < 4; n++) {
                    int rd = n * 16 + lr;
                    float bv = bias[n_base + rd];
#pragma unroll
                    for (int j = 0; j < 4; j++) {
                        int ct = m * 16 + lk * 4 + j;
                        int ct2 = (ct & 32) | (((ct >> 2) & 3) << 3) | (((ct >> 4) & 1) << 2) | (ct & 3);
                        int addr = (rd * 128 + ct2 * 2) ^ ((rd & 7) << 4);
                        *(bf16_t*)(myL + addr) = (bf16_t)(acc[m][n][j] + bv);
                    }
                }
#pragma unroll
            for (int it = 0; it < 8; it++) {
                int row = it * 8 + (lane >> 3);     // dh
                int byte = (lane & 7) * 16;
                bf16x8 val = *(const bf16x8*)(myL + ((row * 128 + byte) ^ ((row & 7) << 4)));
                *(bf16x8*)(vt_out + ((size_t)bh * DH_ + row) * T_ + t0 + (lane & 7) * 8) = val;
            }
        } else {
            bf16_t* dst = which ? k_out : q_out;
            // stage with RoPE: row=t(64), col=dh(64)
#pragma unroll
            for (int m = 0; m < 4; m++)
#pragma unroll
                for (int n = 0; n < 4; n++) {
                    int dh = n * 16 + lr;
                    float bv = bias[n_base + dh];
                    int dh2 = dh >> 1;
                    bool even = (dh & 1) == 0;
#pragma unroll
                    for (int j = 0; j < 4; j++) {
                        int rt = m * 16 + lk * 4 + j;
                        float v = acc[m][n][j] + bv;
                        float p = __shfl_xor(v, 1);   // partner dh^1 lives in lane^1
                        float2 cs = tab[(t0 + rt) * 32 + dh2];
                        float r = even ? v * cs.x - p * cs.y : v * cs.x + p * cs.y;
                        int addr = (rt * 128 + dh * 2) ^ ((rt & 7) << 4);
                        *(bf16_t*)(myL + addr) = (bf16_t)r;
                    }
                }
#pragma unroll
            for (int it = 0; it < 8; it++) {
                int row = it * 8 + (lane >> 3);     // t_local
                int byte = (lane & 7) * 16;
                bf16x8 val = *(const bf16x8*)(myL + ((row * 128 + byte) ^ ((row & 7) << 4)));
                *(bf16x8*)(dst + ((size_t)bh * T_ + t0 + row) * DH_ + (lane & 7) * 8) = val;
            }
        }
    }
}

// ---------------- flash attention, S^T formulation, register softmax ----------
// block = (bh, 64 q rows), 4 waves x 16 q-rows. K/V double-buffered, 1 barrier/step.
__global__ __launch_bounds__(256) void attn64(const bf16_t* __restrict__ Q,
                                              const bf16_t* __restrict__ K,
                                              const bf16_t* __restrict__ Vt,
                                              bf16_t* __restrict__ Ao) {
    __shared__ char smem[32768];   // Ks[2] @0,8K ; Vs[2] @16K,24K

    int tid = threadIdx.x;
    int lane = tid & 63, wid = tid >> 6;
    int lr = lane & 15, lk = lane >> 4;
    // XCD remap: each CU works one bh (K/V reuse), qt spread {q,q+8,q+16,q+24}
    int xcd = blockIdx.x & 7, idx = blockIdx.x >> 3;
    int bh = xcd * 4 + (idx & 3);
    int qt = idx >> 2;
    int q0 = qt * 64;
    int qrel = wid * 16 + lr;                          // q row within block

    const bf16_t* Qp = Q + ((size_t)bh * T_ + q0 + qrel) * DH_;
    bf16x8 qf0 = *(const bf16x8*)(Qp + lk * 8);
    bf16x8 qf1 = *(const bf16x8*)(Qp + 32 + lk * 8);

    f32x4 zz = {0.f, 0.f, 0.f, 0.f};
    f32x4 oacc[4];                                     // O^T: col q=lr, rows dh
#pragma unroll
    for (int dt = 0; dt < 4; dt++) oacc[dt] = zz;
    float mrun = -__builtin_inff(), lsum = 0.f;

    const char* Kbase = (const char*)(K + (size_t)bh * T_ * DH_);
    const char* Vbase = (const char*)(Vt + (size_t)bh * DH_ * T_);

    auto stage = [&](int s, char* Kd, char* Vd) {
        int kv0 = s * 64;
        const char* Kg = Kbase + (size_t)kv0 * 128;
#pragma unroll
        for (int c = 0; c < 2; c++) {
            int o = c * 4096 + tid * 16;
            int r = o >> 7;
            int g = o ^ ((r & 7) << 4);               // pre-swizzled source (involution)
            gld16(Kg + g, Kd + o);
            gld16(Vbase + (size_t)r * (T_ * 2) + kv0 * 2 + (g & 127), Vd + o);
        }
    };

    const float SCL2 = 0.18033688011112042f;           // (1/8) * log2(e)

    auto compute = [&](const char* Kc, const char* Vc, bool dmask) __attribute__((always_inline)) {
        // ---- QK^T -> S^T: col q=lr, row kv = kt*16 + lk*4 + j ----
        float p[4][4];
#pragma unroll
        for (int kt = 0; kt < 4; kt++) {
            int row = kt * 16 + lr;
            int key = (row & 7) << 4;
            bf16x8 kf0 = *(const bf16x8*)(Kc + ((row * 128 + lk * 16) ^ key));
            bf16x8 kf1 = *(const bf16x8*)(Kc + ((row * 128 + 64 + lk * 16) ^ key));
            f32x4 sacc = zz;
            sacc = __builtin_amdgcn_mfma_f32_16x16x32_bf16(kf0, qf0, sacc, 0, 0, 0);
            sacc = __builtin_amdgcn_mfma_f32_16x16x32_bf16(kf1, qf1, sacc, 0, 0, 0);
#pragma unroll
            for (int j = 0; j < 4; j++) {
                float sv = sacc[j] * SCL2;             // base-2 domain
                if (dmask) {
                    int kvrel = kt * 16 + lk * 4 + j;
                    sv = (kvrel <= qrel) ? sv : -__builtin_inff();
                }
                p[kt][j] = sv;
            }
        }
        // ---- online softmax (per-lane: one q row) ----
        float mx = p[0][0];
#pragma unroll
        for (int kt = 0; kt < 4; kt++)
#pragma unroll
            for (int j = 0; j < 4; j++) mx = fmaxf(mx, p[kt][j]);
        mx = fmaxf(mx, __shfl_xor(mx, 16));
        mx = fmaxf(mx, __shfl_xor(mx, 32));
        float mnew = fmaxf(mrun, mx);
        float fac = exp2f(mrun - mnew);
        mrun = mnew;
        float rs = 0.f;
#pragma unroll
        for (int kt = 0; kt < 4; kt++)
#pragma unroll
            for (int j = 0; j < 4; j++) {
                float e = exp2f(p[kt][j] - mnew);
                p[kt][j] = e;
                rs += e;
            }
        rs += __shfl_xor(rs, 16);
        rs += __shfl_xor(rs, 32);
        lsum = lsum * fac + rs;
        // ---- pack P^T B-fragments in-lane (k-slot order matches sigma'd V) ----
        bf16x8 pb0 = { (bf16_t)p[0][0], (bf16_t)p[0][1], (bf16_t)p[0][2], (bf16_t)p[0][3],
                       (bf16_t)p[1][0], (bf16_t)p[1][1], (bf16_t)p[1][2], (bf16_t)p[1][3] };
        bf16x8 pb1 = { (bf16_t)p[2][0], (bf16_t)p[2][1], (bf16_t)p[2][2], (bf16_t)p[2][3],
                       (bf16_t)p[3][0], (bf16_t)p[3][1], (bf16_t)p[3][2], (bf16_t)p[3][3] };
        // ---- rescale O, then PV: O^T += V^T . P ----
#pragma unroll
        for (int dt = 0; dt < 4; dt++) {
            f32x4 o = oacc[dt];
            o[0] *= fac; o[1] *= fac; o[2] *= fac; o[3] *= fac;
            int row = dt * 16 + lr;
            int key = (row & 7) << 4;
            bf16x8 vf0 = *(const bf16x8*)(Vc + ((row * 128 + lk * 16) ^ key));
            bf16x8 vf1 = *(const bf16x8*)(Vc + ((row * 128 + 64 + lk * 16) ^ key));
            o = __builtin_amdgcn_mfma_f32_16x16x32_bf16(vf0, pb0, o, 0, 0, 0);
            o = __builtin_amdgcn_mfma_f32_16x16x32_bf16(vf1, pb1, o, 0, 0, 0);
            oacc[dt] = o;
        }
    };

    stage(0, smem, smem + 16384);
    __syncthreads();
    for (int s = 0; s < qt; ++s) {
        char* Kc = smem + ((s & 1) ? 8192 : 0);
        char* Vc = smem + 16384 + ((s & 1) ? 8192 : 0);
        char* Kn = smem + ((s & 1) ? 0 : 8192);
        char* Vn = smem + 16384 + ((s & 1) ? 0 : 8192);
        stage(s + 1, Kn, Vn);                 // in flight across compute
        compute(Kc, Vc, false);
        __syncthreads();                      // drains prefetch, releases bufs
    }
    {   // diagonal step with causal mask
        char* Kc = smem + ((qt & 1) ? 8192 : 0);
        char* Vc = smem + 16384 + ((qt & 1) ? 8192 : 0);
        compute(Kc, Vc, true);
    }
    __syncthreads();                          // all reads done before restaging

    // ---- write O: stage per-wave [16 q][64 dh] then 128B-row stores ----
    char* myL = smem + wid * 2048;
    float rinv = __builtin_amdgcn_rcpf(lsum);
#pragma unroll
    for (int dt = 0; dt < 4; dt++)
#pragma unroll
        for (int j = 0; j < 4; j++) {
            int dh = dt * 16 + lk * 4 + j;
            int addr = (lr * 128 + dh * 2) ^ ((lr & 7) << 4);
            *(bf16_t*)(myL + addr) = (bf16_t)(oacc[dt][j] * rinv);
        }
    int b = bh >> 4, h = bh & 15;
#pragma unroll
    for (int it = 0; it < 2; it++) {
        int row = it * 8 + (lane >> 3);
        int byte = (lane & 7) * 16;
        bf16x8 val = *(const bf16x8*)(myL + ((row * 128 + byte) ^ ((row & 7) << 4)));
        int t = q0 + wid * 16 + row;
        *(bf16x8*)(Ao + ((size_t)b * T_ + t) * D_ + h * DH_ + (lane & 7) * 8) = val;
    }
}

// ---------------- launch ----------------
extern "C" void kernel_launch(void* const* d_in, const int* in_sizes, int n_in,
                              void* d_out, int out_size, void* d_ws, size_t ws_size,
                              hipStream_t stream) {
    const float* x     = (const float*)d_in[0];
    const float* w_qkv = (const float*)d_in[1];
    const float* b_qkv = (const float*)d_in[2];
    const float* w_out = (const float*)d_in[3];
    const float* b_out = (const float*)d_in[4];
    float* out = (float*)d_out;

    char* ws = (char*)d_ws;
    bf16_t* xb    = (bf16_t*)(ws);               //  8 MB  [4096][1024]
    bf16_t* wqkvb = (bf16_t*)(ws + 8388608);     //  6 MB  [3072][1024]
    bf16_t* wob   = (bf16_t*)(ws + 14680064);    //  2 MB  [1024][1024]
    bf16_t* qb    = (bf16_t*)(ws + 16777216);    //  8 MB  [32][2048][64]
    bf16_t* kb    = (bf16_t*)(ws + 25165824);    //  8 MB  [32][2048][64]
    bf16_t* vtb   = (bf16_t*)(ws + 33554432);    //  8 MB  [32][64][2048] (sigma-permuted t)
    bf16_t* ab    = (bf16_t*)(ws + 41943040);    //  8 MB  [4096][1024]
    float2* tab   = (float2*)(ws + 41943040);    // 512 KB RoPE table, lives in ab region

    rope_tab_k<<<256, 256, 0, stream>>>(tab);
    cvt3<<<8192, 256, 0, stream>>>(x, w_qkv, w_out, xb, wqkvb, wob);

    gemm128<0><<<dim3(24, 32), 256, 0, stream>>>(xb, wqkvb, b_qkv, tab, qb, kb, vtb, nullptr, 1024, 3072);
    attn64<<<1024, 256, 0, stream>>>(qb, kb, vtb, ab);
    gemm128<1><<<dim3(8, 32), 256, 0, stream>>>(ab, wob, b_out, nullptr, nullptr, nullptr, nullptr, out, 1024, 1024);
}

// Round 5
// 115.942 us; speedup vs baseline: 3.5200x; 1.0865x over previous
//
#include <hip/hip_runtime.h>
#include <hip/hip_bf16.h>
#include <math.h>
#include <type_traits>

#define B_ 2
#define T_ 2048
#define D_ 1024
#define H_ 16
#define DH_ 64

typedef __bf16 bf16_t;
typedef bf16_t bf16x8 __attribute__((ext_vector_type(8)));
typedef bf16_t bf16x4 __attribute__((ext_vector_type(4)));
typedef float f32x4 __attribute__((ext_vector_type(4)));

typedef __attribute__((address_space(1))) const void gas_void;
typedef __attribute__((address_space(3))) void las_void;

__device__ __forceinline__ void gld16(const void* g, void* l) {
    __builtin_amdgcn_global_load_lds((gas_void*)g, (las_void*)l, 16, 0, 0);
}

// ---------------- fused fp32 -> bf16 convert (x, w_qkv, w_out) ----------------
__global__ __launch_bounds__(256) void cvt3(const float* __restrict__ a,   // 4194304
                                            const float* __restrict__ b,   // 3145728
                                            const float* __restrict__ c,   // 1048576
                                            bf16_t* __restrict__ oa,
                                            bf16_t* __restrict__ ob,
                                            bf16_t* __restrict__ oc) {
    int i = blockIdx.x * 256 + threadIdx.x;          // vec4 index, 2097152 total
    const float* src; bf16_t* dst; int off;
    if (i < 1048576)      { src = a; dst = oa; off = i; }
    else if (i < 1835008) { src = b; dst = ob; off = i - 1048576; }
    else                  { src = c; dst = oc; off = i - 1835008; }
    float4 f = ((const float4*)src)[off];
    bf16x4 v = { (bf16_t)f.x, (bf16_t)f.y, (bf16_t)f.z, (bf16_t)f.w };
    ((bf16x4*)dst)[off] = v;
}

// ---------------- RoPE cos/sin table: [2048][32] float2 ----------------
__global__ __launch_bounds__(256) void rope_tab_k(float2* __restrict__ tab) {
    int i = blockIdx.x * 256 + threadIdx.x;   // 65536 entries
    int t = i >> 5, d2 = i & 31;
    float invf = exp2f(-(float)d2 * 0.4152410118609203f); // log2(1e4)/32
    float ang = (float)t * invf;
    float sn, cs;
    sincosf(ang, &sn, &cs);
    tab[i] = make_float2(cs, sn);
}

// ---------------- 128x128 GEMM, C = A @ B^T, 3-deep counted-vmcnt pipeline ----
// K must be 1024 (32 steps of BK=32). LDS: 3 x (A 8KB + B 8KB) = 48KB.
// EPI=0: qkv -> RoPE(q,k) -> q[BH][T][64] (q pre-scaled by log2e/8),
//        k[BH][T][64], vT[BH][64][T] (sigma'd t)
// EPI=1: fp32 store with bias
template<int EPI>
__global__ __launch_bounds__(256) void gemm128(const bf16_t* __restrict__ A,
                                               const bf16_t* __restrict__ Bw,
                                               const float* __restrict__ bias,
                                               const float2* __restrict__ tab,
                                               bf16_t* __restrict__ q_out,
                                               bf16_t* __restrict__ k_out,
                                               bf16_t* __restrict__ vt_out,
                                               float* __restrict__ f_out,
                                               int K, int N) {
    __shared__ __align__(16) char smem[49152];
    char* b0 = smem;
    char* b1 = smem + 16384;
    char* b2 = smem + 32768;

    int tid = threadIdx.x;
    int lane = tid & 63, wid = tid >> 6;
    int wr = wid >> 1, wc = wid & 1;
    int lr = lane & 15, lk = lane >> 4;

    // ---- T1: bijective XCD chunking (nwg % 8 == 0) ----
    int l = blockIdx.y * gridDim.x + blockIdx.x;
    int chunk = (gridDim.x * gridDim.y) >> 3;
    int u = (l & 7) * chunk + (l >> 3);
    int bx = u % gridDim.x;
    int by = u / gridDim.x;

    f32x4 acc[4][4];
    f32x4 z = {0.f, 0.f, 0.f, 0.f};
#pragma unroll
    for (int i = 0; i < 4; i++)
#pragma unroll
        for (int j = 0; j < 4; j++) acc[i][j] = z;

    const char* Ab = (const char*)(A + (size_t)by * 128 * K);
    const char* Bb = (const char*)(Bw + (size_t)bx * 128 * K);
    const int rowstride = K * 2;

    // ---- per-thread staging addresses (T2 swizzle baked into global src) ----
    int p0 = tid * 16;                 // physical LDS byte (c=0)
    int p1 = 4096 + tid * 16;          // c=1
    int r0 = p0 >> 6, r1 = p1 >> 6;
    int cb0 = (p0 & 63) ^ (((r0 >> 1) & 3) << 4);
    int cb1 = (p1 & 63) ^ (((r1 >> 1) & 3) << 4);
    size_t gA0 = (size_t)r0 * rowstride + cb0;
    size_t gA1 = (size_t)r1 * rowstride + cb1;

    // ---- fragment read offsets (same swizzle) ----
    int oa[4], ob[4];
#pragma unroll
    for (int m = 0; m < 4; m++) {
        int row = wr * 64 + m * 16 + lr;
        oa[m] = row * 64 + ((lk * 16) ^ (((row >> 1) & 3) << 4));
    }
#pragma unroll
    for (int n = 0; n < 4; n++) {
        int row = wc * 64 + n * 16 + lr;
        ob[n] = row * 64 + ((lk * 16) ^ (((row >> 1) & 3) << 4));
    }

    auto stg = [&](char* buf, int ks) __attribute__((always_inline)) {
        const char* Ag = Ab + (size_t)ks * 64;
        const char* Bg = Bb + (size_t)ks * 64;
        gld16(Ag + gA0, buf + p0);
        gld16(Ag + gA1, buf + p1);
        gld16(Bg + gA0, buf + 8192 + p0);
        gld16(Bg + gA1, buf + 8192 + p1);
    };

    auto iterf = [&](auto vmc, char* buf, int ks, bool dostage) __attribute__((always_inline)) {
        constexpr int VM = decltype(vmc)::value;
        if constexpr (VM == 8)      asm volatile("s_waitcnt vmcnt(8)" ::: "memory");
        else if constexpr (VM == 4) asm volatile("s_waitcnt vmcnt(4)" ::: "memory");
        else                        asm volatile("s_waitcnt vmcnt(0)" ::: "memory");
        __builtin_amdgcn_s_barrier();
        asm volatile("" ::: "memory");
        bf16x8 Af[4], Bf[4];
#pragma unroll
        for (int m = 0; m < 4; m++) Af[m] = *(const bf16x8*)(buf + oa[m]);
#pragma unroll
        for (int n = 0; n < 4; n++) Bf[n] = *(const bf16x8*)(buf + 8192 + ob[n]);
#pragma unroll
        for (int m = 0; m < 4; m++)
#pragma unroll
            for (int n = 0; n < 4; n++)
                acc[m][n] = __builtin_amdgcn_mfma_f32_16x16x32_bf16(Af[m], Bf[n], acc[m][n], 0, 0, 0);
        asm volatile("" ::: "memory");
        __builtin_amdgcn_s_barrier();
        asm volatile("" ::: "memory");
        if (dostage) stg(buf, ks);
    };

    std::integral_constant<int, 8> c8;
    std::integral_constant<int, 4> c4;
    std::integral_constant<int, 0> c0;

    // prologue: stages 0,1,2 in flight
    stg(b0, 0);
    stg(b1, 1);
    stg(b2, 2);
    // steady state: iter u computes stage u, issues stage u+3 into same buffer
    for (int s = 0; s < 30; s += 3) {
        iterf(c8, b0, s + 3, s + 3 < 32);
        iterf(c8, b1, s + 4, s + 4 < 32);
        iterf(c8, b2, s + 5, s + 5 < 32);
    }
    iterf(c4, b0, 0, false);   // u=30
    iterf(c0, b1, 0, false);   // u=31  (drains everything)

    // epilogue: C fragment layout col = lane&15, row = (lane>>4)*4 + j
    int m_base = by * 128 + wr * 64;
    int n_base = bx * 128 + wc * 64;   // multiple of 64
    if (EPI == 1) {
#pragma unroll
        for (int m = 0; m < 4; m++) {
            int gm0 = m_base + m * 16 + lk * 4;
#pragma unroll
            for (int n = 0; n < 4; n++) {
                int nc = n_base + n * 16 + lr;
                float bv = bias[nc];
#pragma unroll
                for (int j = 0; j < 4; j++)
                    f_out[(size_t)(gm0 + j) * N + nc] = acc[m][n][j] + bv;
            }
        }
    } else {
        char* myL = smem + wid * 8192;          // wave-private [64][128B], XOR-swizzled
        int which = n_base >> 10;               // 0=q 1=k 2=v (uniform per wave)
        int h = (n_base & 1023) >> 6;
        int b = m_base >> 11, t0 = m_base & 2047;
        int bh = b * H_ + h;
        if (which == 2) {
            // stage C^T: row=dh(64), col=t(64), t sigma^-1-permuted in 32-blocks
#pragma unroll
            for (int m = 0; m < 4; m++)
#pragma unroll
                for (int n = 0; n < 4; n++) {
                    int rd = n * 16 + lr;
                    float bv = bias[n_base + rd];
#pragma unroll
                    for (int j = 0; j < 4; j++) {
                        int ct = m * 16 + lk * 4 + j;
                        int ct2 = (ct & 32) | (((ct >> 2) & 3) << 3) | (((ct >> 4) & 1) << 2) | (ct & 3);
                        int addr = (rd * 128 + ct2 * 2) ^ ((rd & 7) << 4);
                        *(bf16_t*)(myL + addr) = (bf16_t)(acc[m][n][j] + bv);
                    }
                }
#pragma unroll
            for (int it = 0; it < 8; it++) {
                int row = it * 8 + (lane >> 3);     // dh
                int byte = (lane & 7) * 16;
                bf16x8 val = *(const bf16x8*)(myL + ((row * 128 + byte) ^ ((row & 7) << 4)));
                *(bf16x8*)(vt_out + ((size_t)bh * DH_ + row) * T_ + t0 + (lane & 7) * 8) = val;
            }
        } else {
            bf16_t* dst = which ? k_out : q_out;
            float qscl = which ? 1.0f : 0.18033688011112042f;  // q: fold (1/8)*log2(e)
            // stage with RoPE: row=t(64), col=dh(64)
#pragma unroll
            for (int m = 0; m < 4; m++)
#pragma unroll
                for (int n = 0; n < 4; n++) {
                    int dh = n * 16 + lr;
                    float bv = bias[n_base + dh];
                    int dh2 = dh >> 1;
                    bool even = (dh & 1) == 0;
#pragma unroll
                    for (int j = 0; j < 4; j++) {
                        int rt = m * 16 + lk * 4 + j;
                        float v = acc[m][n][j] + bv;
                        float p = __shfl_xor(v, 1);   // partner dh^1 lives in lane^1
                        float2 cs = tab[(t0 + rt) * 32 + dh2];
                        float r = even ? v * cs.x - p * cs.y : v * cs.x + p * cs.y;
                        r *= qscl;
                        int addr = (rt * 128 + dh * 2) ^ ((rt & 7) << 4);
                        *(bf16_t*)(myL + addr) = (bf16_t)r;
                    }
                }
#pragma unroll
            for (int it = 0; it < 8; it++) {
                int row = it * 8 + (lane >> 3);     // t_local
                int byte = (lane & 7) * 16;
                bf16x8 val = *(const bf16x8*)(myL + ((row * 128 + byte) ^ ((row & 7) << 4)));
                *(bf16x8*)(dst + ((size_t)bh * T_ + t0 + row) * DH_ + (lane & 7) * 8) = val;
            }
        }
    }
}

// ---------------- flash attention, S^T + QK/PV cross-tile pipeline -----------
// block = (bh, 64 q rows), 4 waves x 16 q-rows.
// iter s: [QK(s+1) MFMA] + [PV(s) MFMA] + [softmax(s+1) VALU] overlap.
// K double-buffered, V triple-buffered; 1 barrier + vmcnt(0) per iter
// (loads issued a full iteration earlier; K/V L2-resident).
__global__ __launch_bounds__(256, 4) void attn64(const bf16_t* __restrict__ Q,
                                                 const bf16_t* __restrict__ K,
                                                 const bf16_t* __restrict__ Vt,
                                                 bf16_t* __restrict__ Ao) {
    __shared__ __align__(16) char smem[40960];  // K0@0 K1@8K V0@16K V1@24K V2@32K

    int tid = threadIdx.x;
    int lane = tid & 63, wid = tid >> 6;
    int lr = lane & 15, lk = lane >> 4;
    // XCD remap: 4 bh per XCD (K/V L2-resident); per-CU qt set {q,15-q,16+q,31-q}
    // has constant total work (62 steps) -> balanced makespan.
    int xcd = blockIdx.x & 7, idx = blockIdx.x >> 3;
    int bh = xcd * 4 + (idx & 3);
    int i5 = idx >> 2;                 // 0..31
    int qq = i5 & 7, rr = i5 >> 3;
    int qt = (rr == 0) ? qq : (rr == 1) ? 15 - qq : (rr == 2) ? 16 + qq : 31 - qq;
    int q0 = qt * 64;
    int qrel = wid * 16 + lr;          // q row within block

    const bf16_t* Qp = Q + ((size_t)bh * T_ + q0 + qrel) * DH_;
    bf16x8 qf0 = *(const bf16x8*)(Qp + lk * 8);
    bf16x8 qf1 = *(const bf16x8*)(Qp + 32 + lk * 8);

    f32x4 zz = {0.f, 0.f, 0.f, 0.f};
    f32x4 oacc[4];                     // O^T: col q=lr, rows dh
#pragma unroll
    for (int dt = 0; dt < 4; dt++) oacc[dt] = zz;
    float mrun = -__builtin_inff(), lsum = 0.f;

    const char* Kbase = (const char*)(K + (size_t)bh * T_ * DH_);
    const char* Vbase = (const char*)(Vt + (size_t)bh * DH_ * T_);

    auto stage = [&](int s, char* Kd, char* Vd) __attribute__((always_inline)) {
        int kv0 = s * 64;
        const char* Kg = Kbase + (size_t)kv0 * 128;
#pragma unroll
        for (int c = 0; c < 2; c++) {
            int o = c * 4096 + tid * 16;
            int r = o >> 7;
            int g = o ^ ((r & 7) << 4);               // pre-swizzled source (involution)
            gld16(Kg + g, Kd + o);
            gld16(Vbase + (size_t)r * (T_ * 2) + kv0 * 2 + (g & 127), Vd + o);
        }
    };

    float p[4][4];
    bf16x8 pb0, pb1;

    auto do_qk = [&](const char* Kc, auto dmc) __attribute__((always_inline)) {
        constexpr bool DM = decltype(dmc)::value;
#pragma unroll
        for (int kt = 0; kt < 4; kt++) {
            int row = kt * 16 + lr;
            int key = (row & 7) << 4;
            bf16x8 kf0 = *(const bf16x8*)(Kc + ((row * 128 + lk * 16) ^ key));
            bf16x8 kf1 = *(const bf16x8*)(Kc + ((row * 128 + 64 + lk * 16) ^ key));
            f32x4 sacc = zz;
            sacc = __builtin_amdgcn_mfma_f32_16x16x32_bf16(kf0, qf0, sacc, 0, 0, 0);
            sacc = __builtin_amdgcn_mfma_f32_16x16x32_bf16(kf1, qf1, sacc, 0, 0, 0);
#pragma unroll
            for (int j = 0; j < 4; j++) {
                if (DM) {
                    int kvrel = kt * 16 + lk * 4 + j;
                    p[kt][j] = (kvrel <= qrel) ? sacc[j] : -__builtin_inff();
                } else {
                    p[kt][j] = sacc[j];
                }
            }
        }
    };

    auto do_pv = [&](const char* Vc) __attribute__((always_inline)) {
#pragma unroll
        for (int dt = 0; dt < 4; dt++) {
            int row = dt * 16 + lr;
            int key = (row & 7) << 4;
            bf16x8 vf0 = *(const bf16x8*)(Vc + ((row * 128 + lk * 16) ^ key));
            bf16x8 vf1 = *(const bf16x8*)(Vc + ((row * 128 + 64 + lk * 16) ^ key));
            f32x4 o = oacc[dt];
            o = __builtin_amdgcn_mfma_f32_16x16x32_bf16(vf0, pb0, o, 0, 0, 0);
            o = __builtin_amdgcn_mfma_f32_16x16x32_bf16(vf1, pb1, o, 0, 0, 0);
            oacc[dt] = o;
        }
    };

    auto do_softmax = [&]() __attribute__((always_inline)) {
        float mk[4];
#pragma unroll
        for (int kt = 0; kt < 4; kt++)
            mk[kt] = fmaxf(fmaxf(p[kt][0], p[kt][1]), fmaxf(p[kt][2], p[kt][3]));
        float mx = fmaxf(fmaxf(mk[0], mk[1]), fmaxf(mk[2], mk[3]));
        mx = fmaxf(mx, __shfl_xor(mx, 16));
        mx = fmaxf(mx, __shfl_xor(mx, 32));
        if (!__all(mx <= mrun + 8.f)) {         // T13 defer-max, base-2 domain
            float mnew = fmaxf(mrun, mx);
            float fac = exp2f(mrun - mnew);
            mrun = mnew;
            lsum *= fac;
#pragma unroll
            for (int dt = 0; dt < 4; dt++) oacc[dt] = oacc[dt] * fac;
        }
        float rs = 0.f;
#pragma unroll
        for (int kt = 0; kt < 4; kt++)
#pragma unroll
            for (int j = 0; j < 4; j++) {
                float e = exp2f(p[kt][j] - mrun);
                p[kt][j] = e;
                rs += e;
            }
        rs += __shfl_xor(rs, 16);
        rs += __shfl_xor(rs, 32);
        lsum += rs;
        pb0 = bf16x8{ (bf16_t)p[0][0], (bf16_t)p[0][1], (bf16_t)p[0][2], (bf16_t)p[0][3],
                      (bf16_t)p[1][0], (bf16_t)p[1][1], (bf16_t)p[1][2], (bf16_t)p[1][3] };
        pb1 = bf16x8{ (bf16_t)p[2][0], (bf16_t)p[2][1], (bf16_t)p[2][2], (bf16_t)p[2][3],
                      (bf16_t)p[3][0], (bf16_t)p[3][1], (bf16_t)p[3][2], (bf16_t)p[3][3] };
    };

    std::integral_constant<bool, true>  mask_y;
    std::integral_constant<bool, false> mask_n;

    // ---- prologue: tiles 0,1 in flight; compute tile 0's P ----
    stage(0, smem, smem + 16384);
    stage(1, smem + 8192, smem + 24576);
    asm volatile("s_waitcnt vmcnt(4)" ::: "memory");   // tile 0 landed
    __builtin_amdgcn_s_barrier();
    asm volatile("" ::: "memory");
    if (qt == 0) do_qk(smem, mask_y); else do_qk(smem, mask_n);
    do_softmax();

    char* Kr = smem + 8192;            // holds K(s+1)
    char* Kw = smem;                   // overwritten with K(s+2)
    char* Vr = smem + 16384;           // V(s)
    char* Vn = smem + 24576;           // V(s+1)
    char* Vw = smem + 32768;           // target for V(s+2)

    auto iter = [&](int s, auto dmc) __attribute__((always_inline)) {
        asm volatile("s_waitcnt vmcnt(0)" ::: "memory");  // tile s+1 landed (issued 1 iter ago)
        __builtin_amdgcn_s_barrier();                     // all waves done with Kw/Vw readers
        asm volatile("" ::: "memory");
        if (s + 2 <= qt) stage(s + 2, Kw, Vw);
        do_qk(Kr, dmc);          // MFMA, tile s+1
        do_pv(Vr);               // MFMA, tile s (old pb) — overlaps softmax below
        do_softmax();            // VALU, tile s+1 (rescale lands after PV: correct)
        char* t;
        t = Kr; Kr = Kw; Kw = t;
        t = Vr; Vr = Vn; Vn = Vw; Vw = t;
    };

    for (int s = 0; s + 1 < qt; ++s) iter(s, mask_n);
    if (qt > 0) iter(qt - 1, mask_y);   // diagonal tile masked
    do_pv(Vr);                          // final PV
    __syncthreads();                    // K region about to be reused for staging

    // ---- write O: stage per-wave [16 q][64 dh] then 128B-row stores ----
    char* myL = smem + wid * 2048;
    float rinv = __builtin_amdgcn_rcpf(lsum);
#pragma unroll
    for (int dt = 0; dt < 4; dt++)
#pragma unroll
        for (int j = 0; j < 4; j++) {
            int dh = dt * 16 + lk * 4 + j;
            int addr = (lr * 128 + dh * 2) ^ ((lr & 7) << 4);
            *(bf16_t*)(myL + addr) = (bf16_t)(oacc[dt][j] * rinv);
        }
    int b = bh >> 4, h = bh & 15;
#pragma unroll
    for (int it = 0; it < 2; it++) {
        int row = it * 8 + (lane >> 3);
        int byte = (lane & 7) * 16;
        bf16x8 val = *(const bf16x8*)(myL + ((row * 128 + byte) ^ ((row & 7) << 4)));
        int t = q0 + wid * 16 + row;
        *(bf16x8*)(Ao + ((size_t)b * T_ + t) * D_ + h * DH_ + (lane & 7) * 8) = val;
    }
}

// ---------------- launch ----------------
extern "C" void kernel_launch(void* const* d_in, const int* in_sizes, int n_in,
                              void* d_out, int out_size, void* d_ws, size_t ws_size,
                              hipStream_t stream) {
    const float* x     = (const float*)d_in[0];
    const float* w_qkv = (const float*)d_in[1];
    const float* b_qkv = (const float*)d_in[2];
    const float* w_out = (const float*)d_in[3];
    const float* b_out = (const float*)d_in[4];
    float* out = (float*)d_out;

    char* ws = (char*)d_ws;
    bf16_t* xb    = (bf16_t*)(ws);               //  8 MB  [4096][1024]
    bf16_t* wqkvb = (bf16_t*)(ws + 8388608);     //  6 MB  [3072][1024]
    bf16_t* wob   = (bf16_t*)(ws + 14680064);    //  2 MB  [1024][1024]
    bf16_t* qb    = (bf16_t*)(ws + 16777216);    //  8 MB  [32][2048][64] (pre-scaled)
    bf16_t* kb    = (bf16_t*)(ws + 25165824);    //  8 MB  [32][2048][64]
    bf16_t* vtb   = (bf16_t*)(ws + 33554432);    //  8 MB  [32][64][2048] (sigma-permuted t)
    bf16_t* ab    = (bf16_t*)(ws + 41943040);    //  8 MB  [4096][1024]
    float2* tab   = (float2*)(ws + 41943040);    // 512 KB RoPE table, lives in ab region

    rope_tab_k<<<256, 256, 0, stream>>>(tab);
    cvt3<<<8192, 256, 0, stream>>>(x, w_qkv, w_out, xb, wqkvb, wob);

    gemm128<0><<<dim3(24, 32), 256, 0, stream>>>(xb, wqkvb, b_qkv, tab, qb, kb, vtb, nullptr, 1024, 3072);
    attn64<<<1024, 256, 0, stream>>>(qb, kb, vtb, ab);
    gemm128<1><<<dim3(8, 32), 256, 0, stream>>>(ab, wob, b_out, nullptr, nullptr, nullptr, nullptr, out, 1024, 1024);
}

// Round 6
// 114.501 us; speedup vs baseline: 3.5643x; 1.0126x over previous
//
#include <hip/hip_runtime.h>
#include <hip/hip_bf16.h>
#include <math.h>
#include <type_traits>

#define B_ 2
#define T_ 2048
#define D_ 1024
#define H_ 16
#define DH_ 64

typedef __bf16 bf16_t;
typedef bf16_t bf16x8 __attribute__((ext_vector_type(8)));
typedef bf16_t bf16x4 __attribute__((ext_vector_type(4)));
typedef float f32x4 __attribute__((ext_vector_type(4)));

typedef __attribute__((address_space(1))) const void gas_void;
typedef __attribute__((address_space(3))) void las_void;

__device__ __forceinline__ void gld16(const void* g, void* l) {
    __builtin_amdgcn_global_load_lds((gas_void*)g, (las_void*)l, 16, 0, 0);
}

#define BARRIER() do { asm volatile("" ::: "memory"); __builtin_amdgcn_s_barrier(); asm volatile("" ::: "memory"); } while (0)

// ---------------- fused fp32 -> bf16 convert (x, w_qkv, w_out) ----------------
__global__ __launch_bounds__(256) void cvt3(const float* __restrict__ a,
                                            const float* __restrict__ b,
                                            const float* __restrict__ c,
                                            bf16_t* __restrict__ oa,
                                            bf16_t* __restrict__ ob,
                                            bf16_t* __restrict__ oc) {
    int i = blockIdx.x * 256 + threadIdx.x;          // vec4 index, 2097152 total
    const float* src; bf16_t* dst; int off;
    if (i < 1048576)      { src = a; dst = oa; off = i; }
    else if (i < 1835008) { src = b; dst = ob; off = i - 1048576; }
    else                  { src = c; dst = oc; off = i - 1835008; }
    float4 f = ((const float4*)src)[off];
    bf16x4 v = { (bf16_t)f.x, (bf16_t)f.y, (bf16_t)f.z, (bf16_t)f.w };
    ((bf16x4*)dst)[off] = v;
}

// ---------------- RoPE cos/sin table: [2048][32] float2 ----------------
__global__ __launch_bounds__(256) void rope_tab_k(float2* __restrict__ tab) {
    int i = blockIdx.x * 256 + threadIdx.x;   // 65536 entries
    int t = i >> 5, d2 = i & 31;
    float invf = exp2f(-(float)d2 * 0.4152410118609203f); // log2(1e4)/32
    float ang = (float)t * invf;
    float sn, cs;
    sincosf(ang, &sn, &cs);
    tab[i] = make_float2(cs, sn);
}

// ---------------- 256x256 GEMM (QKV), BK=64, 8 waves, 4-phase/K-tile ---------
// C = A @ B^T.  A [4096][1024] bf16, Bw [3072][1024] bf16.  K=1024 = 16 tiles.
// LDS 128KB: parity p: A at p*32768 (2 halves of 16KB), B at 65536+p*32768.
// Counted vmcnt(2) once per K-tile; per-phase {reads; stage; bar; MFMA; bar}.
// Epilogue: RoPE(q,k) -> q[BH][T][64] (q pre-scaled log2e/8), k[BH][T][64],
//           vT[BH][64][T] with sigma^-1-permuted t (matches attn's P k-slots).
__global__ __launch_bounds__(512, 1) void gemm256qkv(const bf16_t* __restrict__ A,
                                                     const bf16_t* __restrict__ Bw,
                                                     const float* __restrict__ bias,
                                                     const float2* __restrict__ tab,
                                                     bf16_t* __restrict__ q_out,
                                                     bf16_t* __restrict__ k_out,
                                                     bf16_t* __restrict__ vt_out) {
    __shared__ __align__(16) char smem[131072];

    int tid = threadIdx.x;
    int lane = tid & 63, wid = tid >> 6;
    int wm = wid >> 2, wn = wid & 3;          // wave grid 2M x 4N
    int lr = lane & 15, lk = lane >> 4;

    // XCD chunking: 192 blocks, 24/XCD = 2 by-rows x 12 bx (bijective)
    int l = blockIdx.y * 12 + blockIdx.x;
    int x = l & 7, c = l >> 3;                // c in [0,24)
    int by = x * 2 + (c >= 12);
    int bx = (c >= 12) ? c - 12 : c;

    f32x4 acc[8][4];
    f32x4 z = {0.f, 0.f, 0.f, 0.f};
#pragma unroll
    for (int i = 0; i < 8; i++)
#pragma unroll
        for (int j = 0; j < 4; j++) acc[i][j] = z;

    // ---- staging addresses (swizzle baked into global source; LDS dest linear)
    int colb = (tid * 16) & 127;              // in-row byte
    int rb = tid >> 3;                        // row 0..63 (slot0); slot1 = +64
    int csw = colb ^ ((rb & 7) << 4);         // involution, shared by both slots
    const char* gA = (const char*)A + (size_t)(by * 256 + rb) * 2048 + csw;
    const char* gB = (const char*)Bw + (size_t)(bx * 256 + rb) * 2048 + csw;

    auto stgA = [&](int par, int h, int kt) __attribute__((always_inline)) {
        char* d = smem + par * 32768 + h * 16384;
        const char* g = gA + (size_t)h * 262144 + kt * 128;
        gld16(g, d + tid * 16);
        gld16(g + 131072, d + 8192 + tid * 16);
    };
    auto stgB = [&](int par, int h, int kt) __attribute__((always_inline)) {
        char* d = smem + 65536 + par * 32768 + h * 16384;
        const char* g = gB + (size_t)h * 262144 + kt * 128;
        gld16(g, d + tid * 16);
        gld16(g + 131072, d + 8192 + tid * 16);
    };

    // ---- fragment read offsets ----
    int swz = (lr & 7) << 4;
    int ca0 = (lk * 16) ^ swz;                // ks=0
    int ca1 = (64 + lk * 16) ^ swz;           // ks=1

    bf16x8 Af[2][2], Bf[4][2];
    auto rdB = [&](const char* cB) __attribute__((always_inline)) {
        const char* base = cB + (wn >> 1) * 16384 + ((wn & 1) * 64) * 128 + lr * 128;
#pragma unroll
        for (int n = 0; n < 4; n++) {
            Bf[n][0] = *(const bf16x8*)(base + n * 2048 + ca0);
            Bf[n][1] = *(const bf16x8*)(base + n * 2048 + ca1);
        }
    };
    auto rdA = [&](const char* cA, int mp) __attribute__((always_inline)) {
        const char* base = cA + wm * 16384 + lr * 128;
#pragma unroll
        for (int mm = 0; mm < 2; mm++) {
            Af[mm][0] = *(const bf16x8*)(base + (mp * 2 + mm) * 2048 + ca0);
            Af[mm][1] = *(const bf16x8*)(base + (mp * 2 + mm) * 2048 + ca1);
        }
    };
    auto mfmaset = [&](int q) __attribute__((always_inline)) {
        __builtin_amdgcn_s_setprio(1);
#pragma unroll
        for (int mm = 0; mm < 2; mm++)
#pragma unroll
            for (int n = 0; n < 4; n++)
#pragma unroll
                for (int ks = 0; ks < 2; ks++)
                    acc[q * 2 + mm][n] = __builtin_amdgcn_mfma_f32_16x16x32_bf16(
                        Af[mm][ks], Bf[n][ks], acc[q * 2 + mm][n], 0, 0, 0);
        __builtin_amdgcn_s_setprio(0);
    };

    // ---- prologue: K-tile 0 fully staged into parity 0 ----
    stgA(0, 0, 0); stgA(0, 1, 0); stgB(0, 0, 0); stgB(0, 1, 0);

    // ---- main loop: kt = 0..14 stage kt+1 (one half per phase), counted vmcnt
    for (int kt = 0; kt < 15; ++kt) {
        int p = kt & 1, np = p ^ 1;
        const char* cA = smem + p * 32768;
        const char* cB = smem + 65536 + p * 32768;
        stgA(np, 0, kt + 1);                               // item0 (after prev closing bar)
        asm volatile("s_waitcnt vmcnt(2)" ::: "memory");   // forces kt's 8 loads
        BARRIER();                                         // kt data valid, all waves
        rdB(cB); rdA(cA, 0); stgA(np, 1, kt + 1);
        BARRIER(); mfmaset(0); BARRIER();
        rdA(cA, 1); stgB(np, 0, kt + 1);
        BARRIER(); mfmaset(1); BARRIER();
        rdA(cA, 2); stgB(np, 1, kt + 1);
        BARRIER(); mfmaset(2); BARRIER();
        rdA(cA, 3);
        BARRIER(); mfmaset(3); BARRIER();
    }
    {   // kt = 15 (parity 1), no stages, full drain
        const char* cA = smem + 32768;
        const char* cB = smem + 65536 + 32768;
        asm volatile("s_waitcnt vmcnt(0)" ::: "memory");
        BARRIER();
        rdB(cB); rdA(cA, 0); BARRIER(); mfmaset(0); BARRIER();
        rdA(cA, 1); BARRIER(); mfmaset(1); BARRIER();
        rdA(cA, 2); BARRIER(); mfmaset(2); BARRIER();
        rdA(cA, 3); BARRIER(); mfmaset(3); BARRIER();
    }

    // ---- epilogue: per-wave 128x64 tile via wave-private 16KB LDS ----
    int m_base = by * 256 + wm * 128;
    int n_base = bx * 256 + wn * 64;
    char* myL = smem + wid * 16384;
    int which = n_base >> 10;                 // 0=q 1=k 2=v (uniform per wave)
    int h = (n_base & 1023) >> 6;
    int b = m_base >> 11, t0 = m_base & 2047;
    int bh = b * H_ + h;
    if (which == 2) {
        // stage C^T [64 dh][128 t] (256B rows), t sigma^-1-permuted in 32-blocks
#pragma unroll
        for (int m = 0; m < 8; m++)
#pragma unroll
            for (int n = 0; n < 4; n++) {
                int rd = n * 16 + lr;
                float bv = bias[n_base + rd];
#pragma unroll
                for (int j = 0; j < 4; j++) {
                    int ct = m * 16 + lk * 4 + j;
                    int ct2 = (ct & 96) | (((ct >> 2) & 3) << 3) | (((ct >> 4) & 1) << 2) | (ct & 3);
                    int addr = (rd * 256 + ct2 * 2) ^ ((rd & 7) << 4);
                    *(bf16_t*)(myL + addr) = (bf16_t)(acc[m][n][j] + bv);
                }
            }
#pragma unroll
        for (int it = 0; it < 16; it++) {
            int row = it * 4 + (lane >> 4);   // dh
            int byt = (lane & 15) * 16;
            bf16x8 val = *(const bf16x8*)(myL + ((row * 256 + byt) ^ ((row & 7) << 4)));
            *(bf16x8*)(vt_out + ((size_t)bh * DH_ + row) * T_ + t0 + (lane & 15) * 8) = val;
        }
    } else {
        bf16_t* dst = which ? k_out : q_out;
        float qscl = which ? 1.0f : 0.18033688011112042f;  // q: fold (1/8)*log2(e)
#pragma unroll
        for (int m = 0; m < 8; m++)
#pragma unroll
            for (int n = 0; n < 4; n++) {
                int dh = n * 16 + lr;
                float bv = bias[n_base + dh];
                int dh2 = dh >> 1;
                bool even = (dh & 1) == 0;
#pragma unroll
                for (int j = 0; j < 4; j++) {
                    int rt = m * 16 + lk * 4 + j;
                    float v = acc[m][n][j] + bv;
                    float pp = __shfl_xor(v, 1);           // partner dh^1 in lane^1
                    float2 cs = tab[(t0 + rt) * 32 + dh2];
                    float r = even ? v * cs.x - pp * cs.y : v * cs.x + pp * cs.y;
                    r *= qscl;
                    int addr = (rt * 128 + dh * 2) ^ ((rt & 7) << 4);
                    *(bf16_t*)(myL + addr) = (bf16_t)r;
                }
            }
#pragma unroll
        for (int it = 0; it < 16; it++) {
            int row = it * 8 + (lane >> 3);   // t_local
            int byt = (lane & 7) * 16;
            bf16x8 val = *(const bf16x8*)(myL + ((row * 128 + byt) ^ ((row & 7) << 4)));
            *(bf16x8*)(dst + ((size_t)bh * T_ + t0 + row) * DH_ + (lane & 7) * 8) = val;
        }
    }
}

// ---------------- 128x128 GEMM (out-proj), 3-deep counted-vmcnt pipeline -----
__global__ __launch_bounds__(256) void gemm128o(const bf16_t* __restrict__ A,
                                                const bf16_t* __restrict__ Bw,
                                                const float* __restrict__ bias,
                                                float* __restrict__ f_out,
                                                int K, int N) {
    __shared__ __align__(16) char smem[49152];
    char* b0 = smem;
    char* b1 = smem + 16384;
    char* b2 = smem + 32768;

    int tid = threadIdx.x;
    int lane = tid & 63, wid = tid >> 6;
    int wr = wid >> 1, wc = wid & 1;
    int lr = lane & 15, lk = lane >> 4;

    int l = blockIdx.y * gridDim.x + blockIdx.x;
    int chunk = (gridDim.x * gridDim.y) >> 3;
    int u = (l & 7) * chunk + (l >> 3);
    int bx = u % gridDim.x;
    int by = u / gridDim.x;

    f32x4 acc[4][4];
    f32x4 z = {0.f, 0.f, 0.f, 0.f};
#pragma unroll
    for (int i = 0; i < 4; i++)
#pragma unroll
        for (int j = 0; j < 4; j++) acc[i][j] = z;

    const char* Ab = (const char*)(A + (size_t)by * 128 * K);
    const char* Bb = (const char*)(Bw + (size_t)bx * 128 * K);
    const int rowstride = K * 2;

    int p0 = tid * 16;
    int p1 = 4096 + tid * 16;
    int r0 = p0 >> 6, r1 = p1 >> 6;
    int cb0 = (p0 & 63) ^ (((r0 >> 1) & 3) << 4);
    int cb1 = (p1 & 63) ^ (((r1 >> 1) & 3) << 4);
    size_t gA0 = (size_t)r0 * rowstride + cb0;
    size_t gA1 = (size_t)r1 * rowstride + cb1;

    int oa[4], ob[4];
#pragma unroll
    for (int m = 0; m < 4; m++) {
        int row = wr * 64 + m * 16 + lr;
        oa[m] = row * 64 + ((lk * 16) ^ (((row >> 1) & 3) << 4));
    }
#pragma unroll
    for (int n = 0; n < 4; n++) {
        int row = wc * 64 + n * 16 + lr;
        ob[n] = row * 64 + ((lk * 16) ^ (((row >> 1) & 3) << 4));
    }

    auto stg = [&](char* buf, int ks) __attribute__((always_inline)) {
        const char* Ag = Ab + (size_t)ks * 64;
        const char* Bg = Bb + (size_t)ks * 64;
        gld16(Ag + gA0, buf + p0);
        gld16(Ag + gA1, buf + p1);
        gld16(Bg + gA0, buf + 8192 + p0);
        gld16(Bg + gA1, buf + 8192 + p1);
    };

    auto iterf = [&](auto vmc, char* buf, int ks, bool dostage) __attribute__((always_inline)) {
        constexpr int VM = decltype(vmc)::value;
        if constexpr (VM == 8)      asm volatile("s_waitcnt vmcnt(8)" ::: "memory");
        else if constexpr (VM == 4) asm volatile("s_waitcnt vmcnt(4)" ::: "memory");
        else                        asm volatile("s_waitcnt vmcnt(0)" ::: "memory");
        __builtin_amdgcn_s_barrier();
        asm volatile("" ::: "memory");
        bf16x8 Af[4], Bf[4];
#pragma unroll
        for (int m = 0; m < 4; m++) Af[m] = *(const bf16x8*)(buf + oa[m]);
#pragma unroll
        for (int n = 0; n < 4; n++) Bf[n] = *(const bf16x8*)(buf + 8192 + ob[n]);
#pragma unroll
        for (int m = 0; m < 4; m++)
#pragma unroll
            for (int n = 0; n < 4; n++)
                acc[m][n] = __builtin_amdgcn_mfma_f32_16x16x32_bf16(Af[m], Bf[n], acc[m][n], 0, 0, 0);
        asm volatile("" ::: "memory");
        __builtin_amdgcn_s_barrier();
        asm volatile("" ::: "memory");
        if (dostage) stg(buf, ks);
    };

    std::integral_constant<int, 8> c8;
    std::integral_constant<int, 4> c4;
    std::integral_constant<int, 0> c0;

    stg(b0, 0);
    stg(b1, 1);
    stg(b2, 2);
    for (int s = 0; s < 30; s += 3) {
        iterf(c8, b0, s + 3, s + 3 < 32);
        iterf(c8, b1, s + 4, s + 4 < 32);
        iterf(c8, b2, s + 5, s + 5 < 32);
    }
    iterf(c4, b0, 0, false);
    iterf(c0, b1, 0, false);

    int m_base = by * 128 + wr * 64;
    int n_base = bx * 128 + wc * 64;
#pragma unroll
    for (int m = 0; m < 4; m++) {
        int gm0 = m_base + m * 16 + lk * 4;
#pragma unroll
        for (int n = 0; n < 4; n++) {
            int nc = n_base + n * 16 + lr;
            float bv = bias[nc];
#pragma unroll
            for (int j = 0; j < 4; j++)
                f_out[(size_t)(gm0 + j) * N + nc] = acc[m][n][j] + bv;
        }
    }
}

// ---------------- flash attention, S^T + QK/PV cross-tile pipeline -----------
__global__ __launch_bounds__(256, 4) void attn64(const bf16_t* __restrict__ Q,
                                                 const bf16_t* __restrict__ K,
                                                 const bf16_t* __restrict__ Vt,
                                                 bf16_t* __restrict__ Ao) {
    __shared__ __align__(16) char smem[40960];  // K0@0 K1@8K V0@16K V1@24K V2@32K

    int tid = threadIdx.x;
    int lane = tid & 63, wid = tid >> 6;
    int lr = lane & 15, lk = lane >> 4;
    int xcd = blockIdx.x & 7, idx = blockIdx.x >> 3;
    int bh = xcd * 4 + (idx & 3);
    int i5 = idx >> 2;                 // 0..31
    int qq = i5 & 7, rr = i5 >> 3;
    int qt = (rr == 0) ? qq : (rr == 1) ? 15 - qq : (rr == 2) ? 16 + qq : 31 - qq;
    int q0 = qt * 64;
    int qrel = wid * 16 + lr;

    const bf16_t* Qp = Q + ((size_t)bh * T_ + q0 + qrel) * DH_;
    bf16x8 qf0 = *(const bf16x8*)(Qp + lk * 8);
    bf16x8 qf1 = *(const bf16x8*)(Qp + 32 + lk * 8);

    f32x4 zz = {0.f, 0.f, 0.f, 0.f};
    f32x4 oacc[4];
#pragma unroll
    for (int dt = 0; dt < 4; dt++) oacc[dt] = zz;
    float mrun = -__builtin_inff(), lsum = 0.f;

    const char* Kbase = (const char*)(K + (size_t)bh * T_ * DH_);
    const char* Vbase = (const char*)(Vt + (size_t)bh * DH_ * T_);

    auto stage = [&](int s, char* Kd, char* Vd) __attribute__((always_inline)) {
        int kv0 = s * 64;
        const char* Kg = Kbase + (size_t)kv0 * 128;
#pragma unroll
        for (int c = 0; c < 2; c++) {
            int o = c * 4096 + tid * 16;
            int r = o >> 7;
            int g = o ^ ((r & 7) << 4);
            gld16(Kg + g, Kd + o);
            gld16(Vbase + (size_t)r * (T_ * 2) + kv0 * 2 + (g & 127), Vd + o);
        }
    };

    float p[4][4];
    bf16x8 pb0, pb1;

    auto do_qk = [&](const char* Kc, auto dmc) __attribute__((always_inline)) {
        constexpr bool DM = decltype(dmc)::value;
#pragma unroll
        for (int kt = 0; kt < 4; kt++) {
            int row = kt * 16 + lr;
            int key = (row & 7) << 4;
            bf16x8 kf0 = *(const bf16x8*)(Kc + ((row * 128 + lk * 16) ^ key));
            bf16x8 kf1 = *(const bf16x8*)(Kc + ((row * 128 + 64 + lk * 16) ^ key));
            f32x4 sacc = zz;
            sacc = __builtin_amdgcn_mfma_f32_16x16x32_bf16(kf0, qf0, sacc, 0, 0, 0);
            sacc = __builtin_amdgcn_mfma_f32_16x16x32_bf16(kf1, qf1, sacc, 0, 0, 0);
#pragma unroll
            for (int j = 0; j < 4; j++) {
                if (DM) {
                    int kvrel = kt * 16 + lk * 4 + j;
                    p[kt][j] = (kvrel <= qrel) ? sacc[j] : -__builtin_inff();
                } else {
                    p[kt][j] = sacc[j];
                }
            }
        }
    };

    auto do_pv = [&](const char* Vc) __attribute__((always_inline)) {
#pragma unroll
        for (int dt = 0; dt < 4; dt++) {
            int row = dt * 16 + lr;
            int key = (row & 7) << 4;
            bf16x8 vf0 = *(const bf16x8*)(Vc + ((row * 128 + lk * 16) ^ key));
            bf16x8 vf1 = *(const bf16x8*)(Vc + ((row * 128 + 64 + lk * 16) ^ key));
            f32x4 o = oacc[dt];
            o = __builtin_amdgcn_mfma_f32_16x16x32_bf16(vf0, pb0, o, 0, 0, 0);
            o = __builtin_amdgcn_mfma_f32_16x16x32_bf16(vf1, pb1, o, 0, 0, 0);
            oacc[dt] = o;
        }
    };

    auto do_softmax = [&]() __attribute__((always_inline)) {
        float mk[4];
#pragma unroll
        for (int kt = 0; kt < 4; kt++)
            mk[kt] = fmaxf(fmaxf(p[kt][0], p[kt][1]), fmaxf(p[kt][2], p[kt][3]));
        float mx = fmaxf(fmaxf(mk[0], mk[1]), fmaxf(mk[2], mk[3]));
        mx = fmaxf(mx, __shfl_xor(mx, 16));
        mx = fmaxf(mx, __shfl_xor(mx, 32));
        if (!__all(mx <= mrun + 8.f)) {
            float mnew = fmaxf(mrun, mx);
            float fac = exp2f(mrun - mnew);
            mrun = mnew;
            lsum *= fac;
#pragma unroll
            for (int dt = 0; dt < 4; dt++) oacc[dt] = oacc[dt] * fac;
        }
        float rs = 0.f;
#pragma unroll
        for (int kt = 0; kt < 4; kt++)
#pragma unroll
            for (int j = 0; j < 4; j++) {
                float e = exp2f(p[kt][j] - mrun);
                p[kt][j] = e;
                rs += e;
            }
        rs += __shfl_xor(rs, 16);
        rs += __shfl_xor(rs, 32);
        lsum += rs;
        pb0 = bf16x8{ (bf16_t)p[0][0], (bf16_t)p[0][1], (bf16_t)p[0][2], (bf16_t)p[0][3],
                      (bf16_t)p[1][0], (bf16_t)p[1][1], (bf16_t)p[1][2], (bf16_t)p[1][3] };
        pb1 = bf16x8{ (bf16_t)p[2][0], (bf16_t)p[2][1], (bf16_t)p[2][2], (bf16_t)p[2][3],
                      (bf16_t)p[3][0], (bf16_t)p[3][1], (bf16_t)p[3][2], (bf16_t)p[3][3] };
    };

    std::integral_constant<bool, true>  mask_y;
    std::integral_constant<bool, false> mask_n;

    stage(0, smem, smem + 16384);
    stage(1, smem + 8192, smem + 24576);
    asm volatile("s_waitcnt vmcnt(4)" ::: "memory");
    __builtin_amdgcn_s_barrier();
    asm volatile("" ::: "memory");
    if (qt == 0) do_qk(smem, mask_y); else do_qk(smem, mask_n);
    do_softmax();

    char* Kr = smem + 8192;
    char* Kw = smem;
    char* Vr = smem + 16384;
    char* Vn = smem + 24576;
    char* Vw = smem + 32768;

    auto iter = [&](int s, auto dmc) __attribute__((always_inline)) {
        asm volatile("s_waitcnt vmcnt(0)" ::: "memory");
        __builtin_amdgcn_s_barrier();
        asm volatile("" ::: "memory");
        if (s + 2 <= qt) stage(s + 2, Kw, Vw);
        do_qk(Kr, dmc);
        do_pv(Vr);
        do_softmax();
        char* t;
        t = Kr; Kr = Kw; Kw = t;
        t = Vr; Vr = Vn; Vn = Vw; Vw = t;
    };

    for (int s = 0; s + 1 < qt; ++s) iter(s, mask_n);
    if (qt > 0) iter(qt - 1, mask_y);
    do_pv(Vr);
    __syncthreads();

    char* myL = smem + wid * 2048;
    float rinv = __builtin_amdgcn_rcpf(lsum);
#pragma unroll
    for (int dt = 0; dt < 4; dt++)
#pragma unroll
        for (int j = 0; j < 4; j++) {
            int dh = dt * 16 + lk * 4 + j;
            int addr = (lr * 128 + dh * 2) ^ ((lr & 7) << 4);
            *(bf16_t*)(myL + addr) = (bf16_t)(oacc[dt][j] * rinv);
        }
    int b = bh >> 4, h = bh & 15;
#pragma unroll
    for (int it = 0; it < 2; it++) {
        int row = it * 8 + (lane >> 3);
        int byt = (lane & 7) * 16;
        bf16x8 val = *(const bf16x8*)(myL + ((row * 128 + byt) ^ ((row & 7) << 4)));
        int t = q0 + wid * 16 + row;
        *(bf16x8*)(Ao + ((size_t)b * T_ + t) * D_ + h * DH_ + (lane & 7) * 8) = val;
    }
}

// ---------------- launch ----------------
extern "C" void kernel_launch(void* const* d_in, const int* in_sizes, int n_in,
                              void* d_out, int out_size, void* d_ws, size_t ws_size,
                              hipStream_t stream) {
    const float* x     = (const float*)d_in[0];
    const float* w_qkv = (const float*)d_in[1];
    const float* b_qkv = (const float*)d_in[2];
    const float* w_out = (const float*)d_in[3];
    const float* b_out = (const float*)d_in[4];
    float* out = (float*)d_out;

    char* ws = (char*)d_ws;
    bf16_t* xb    = (bf16_t*)(ws);               //  8 MB  [4096][1024]
    bf16_t* wqkvb = (bf16_t*)(ws + 8388608);     //  6 MB  [3072][1024]
    bf16_t* wob   = (bf16_t*)(ws + 14680064);    //  2 MB  [1024][1024]
    bf16_t* qb    = (bf16_t*)(ws + 16777216);    //  8 MB  [32][2048][64] (pre-scaled)
    bf16_t* kb    = (bf16_t*)(ws + 25165824);    //  8 MB  [32][2048][64]
    bf16_t* vtb   = (bf16_t*)(ws + 33554432);    //  8 MB  [32][64][2048] (sigma-permuted t)
    bf16_t* ab    = (bf16_t*)(ws + 41943040);    //  8 MB  [4096][1024]
    float2* tab   = (float2*)(ws + 41943040);    // 512 KB RoPE table, lives in ab region

    rope_tab_k<<<256, 256, 0, stream>>>(tab);
    cvt3<<<8192, 256, 0, stream>>>(x, w_qkv, w_out, xb, wqkvb, wob);

    gemm256qkv<<<dim3(12, 16), 512, 0, stream>>>(xb, wqkvb, b_qkv, tab, qb, kb, vtb);
    attn64<<<1024, 256, 0, stream>>>(qb, kb, vtb, ab);
    gemm128o<<<dim3(8, 32), 256, 0, stream>>>(ab, wob, b_out, out, 1024, 1024);
}

// Round 7
// 107.139 us; speedup vs baseline: 3.8092x; 1.0687x over previous
//
#include <hip/hip_runtime.h>
#include <hip/hip_bf16.h>
#include <math.h>
#include <type_traits>

#define B_ 2
#define T_ 2048
#define D_ 1024
#define H_ 16
#define DH_ 64

typedef __bf16 bf16_t;
typedef bf16_t bf16x8 __attribute__((ext_vector_type(8)));
typedef bf16_t bf16x4 __attribute__((ext_vector_type(4)));
typedef float f32x4 __attribute__((ext_vector_type(4)));

typedef __attribute__((address_space(1))) const void gas_void;
typedef __attribute__((address_space(3))) void las_void;

__device__ __forceinline__ void gld16(const void* g, void* l) {
    __builtin_amdgcn_global_load_lds((gas_void*)g, (las_void*)l, 16, 0, 0);
}

#define BARRIER() do { asm volatile("" ::: "memory"); __builtin_amdgcn_s_barrier(); asm volatile("" ::: "memory"); } while (0)

// ------- fused fp32->bf16 convert (x, w_qkv, w_out) + RoPE table -------------
__global__ __launch_bounds__(256) void cvt3(const float* __restrict__ a,
                                            const float* __restrict__ b,
                                            const float* __restrict__ c,
                                            bf16_t* __restrict__ oa,
                                            bf16_t* __restrict__ ob,
                                            bf16_t* __restrict__ oc,
                                            float2* __restrict__ tab) {
    if (blockIdx.x >= 8192) {                         // RoPE table: [2048][32] float2
        int j = (blockIdx.x - 8192) * 256 + threadIdx.x;   // 65536 entries
        int t = j >> 5, d2 = j & 31;
        float invf = exp2f(-(float)d2 * 0.4152410118609203f); // log2(1e4)/32
        float ang = (float)t * invf;
        float sn, cs;
        sincosf(ang, &sn, &cs);
        tab[j] = make_float2(cs, sn);
        return;
    }
    int i = blockIdx.x * 256 + threadIdx.x;          // vec4 index, 2097152 total
    const float* src; bf16_t* dst; int off;
    if (i < 1048576)      { src = a; dst = oa; off = i; }
    else if (i < 1835008) { src = b; dst = ob; off = i - 1048576; }
    else                  { src = c; dst = oc; off = i - 1835008; }
    float4 f = ((const float4*)src)[off];
    bf16x4 v = { (bf16_t)f.x, (bf16_t)f.y, (bf16_t)f.z, (bf16_t)f.w };
    ((bf16x4*)dst)[off] = v;
}

// ---------------- 256x256 GEMM (QKV), BK=64, 8 waves ------------------------
// ONE barrier + ONE vmcnt(0) per K-tile; free compute region lets the compiler
// interleave ds_read / MFMA / global_load_lds, and 2 waves/SIMD slip.
// Buffer safety: staging during kt targets parity np, whose last readers
// (kt-1) retired before kt's opening barrier; kt's loads were issued one full
// region earlier so vmcnt(0) is cheap.
__global__ __launch_bounds__(512, 2) void gemm256qkv(const bf16_t* __restrict__ A,
                                                     const bf16_t* __restrict__ Bw,
                                                     const float* __restrict__ bias,
                                                     const float2* __restrict__ tab,
                                                     bf16_t* __restrict__ q_out,
                                                     bf16_t* __restrict__ k_out,
                                                     bf16_t* __restrict__ vt_out) {
    __shared__ __align__(16) char smem[131072];

    int tid = threadIdx.x;
    int lane = tid & 63, wid = tid >> 6;
    int wm = wid >> 2, wn = wid & 3;          // wave grid 2M x 4N
    int lr = lane & 15, lk = lane >> 4;

    // XCD chunking: 192 blocks, 24/XCD = 2 by-rows x 12 bx (bijective)
    int l = blockIdx.y * 12 + blockIdx.x;
    int x = l & 7, c = l >> 3;                // c in [0,24)
    int by = x * 2 + (c >= 12);
    int bx = (c >= 12) ? c - 12 : c;

    f32x4 acc[8][4];
    f32x4 z = {0.f, 0.f, 0.f, 0.f};
#pragma unroll
    for (int i = 0; i < 8; i++)
#pragma unroll
        for (int j = 0; j < 4; j++) acc[i][j] = z;

    // ---- staging addresses (swizzle baked into global source; LDS dest linear)
    int colb = (tid * 16) & 127;              // in-row byte
    int rb = tid >> 3;                        // row 0..63 (slot0); slot1 = +64
    int csw = colb ^ ((rb & 7) << 4);         // involution, shared by both slots
    const char* gA = (const char*)A + (size_t)(by * 256 + rb) * 2048 + csw;
    const char* gB = (const char*)Bw + (size_t)(bx * 256 + rb) * 2048 + csw;

    auto stgA = [&](int par, int h, int kt) __attribute__((always_inline)) {
        char* d = smem + par * 32768 + h * 16384;
        const char* g = gA + (size_t)h * 262144 + kt * 128;
        gld16(g, d + tid * 16);
        gld16(g + 131072, d + 8192 + tid * 16);
    };
    auto stgB = [&](int par, int h, int kt) __attribute__((always_inline)) {
        char* d = smem + 65536 + par * 32768 + h * 16384;
        const char* g = gB + (size_t)h * 262144 + kt * 128;
        gld16(g, d + tid * 16);
        gld16(g + 131072, d + 8192 + tid * 16);
    };

    // ---- fragment read offsets ----
    int swz = (lr & 7) << 4;
    int ca0 = (lk * 16) ^ swz;                // ks=0
    int ca1 = (64 + lk * 16) ^ swz;           // ks=1

    bf16x8 Af[2][2], Bf[4][2];
    auto rdB = [&](const char* cB) __attribute__((always_inline)) {
        const char* base = cB + (wn >> 1) * 16384 + ((wn & 1) * 64) * 128 + lr * 128;
#pragma unroll
        for (int n = 0; n < 4; n++) {
            Bf[n][0] = *(const bf16x8*)(base + n * 2048 + ca0);
            Bf[n][1] = *(const bf16x8*)(base + n * 2048 + ca1);
        }
    };
    auto rdA = [&](const char* cA, int mp) __attribute__((always_inline)) {
        const char* base = cA + wm * 16384 + lr * 128;
#pragma unroll
        for (int mm = 0; mm < 2; mm++) {
            Af[mm][0] = *(const bf16x8*)(base + (mp * 2 + mm) * 2048 + ca0);
            Af[mm][1] = *(const bf16x8*)(base + (mp * 2 + mm) * 2048 + ca1);
        }
    };
    auto mfmaset = [&](int q) __attribute__((always_inline)) {
        __builtin_amdgcn_s_setprio(1);
#pragma unroll
        for (int mm = 0; mm < 2; mm++)
#pragma unroll
            for (int n = 0; n < 4; n++)
#pragma unroll
                for (int ks = 0; ks < 2; ks++)
                    acc[q * 2 + mm][n] = __builtin_amdgcn_mfma_f32_16x16x32_bf16(
                        Af[mm][ks], Bf[n][ks], acc[q * 2 + mm][n], 0, 0, 0);
        __builtin_amdgcn_s_setprio(0);
    };

    // ---- prologue: K-tile 0 fully staged into parity 0 ----
    stgA(0, 0, 0); stgA(0, 1, 0); stgB(0, 0, 0); stgB(0, 1, 0);

    for (int kt = 0; kt < 16; ++kt) {
        int p = kt & 1, np = p ^ 1;
        const char* cA = smem + p * 32768;
        const char* cB = smem + 65536 + p * 32768;
        asm volatile("s_waitcnt vmcnt(0)" ::: "memory");   // tile kt landed
        BARRIER();                                         // + parity np free
        bool st = kt < 15;
        rdB(cB);
        if (st) { stgA(np, 0, kt + 1); stgA(np, 1, kt + 1); }
        rdA(cA, 0);
        if (st) stgB(np, 0, kt + 1);
        mfmaset(0);
        rdA(cA, 1);
        if (st) stgB(np, 1, kt + 1);
        mfmaset(1);
        rdA(cA, 2);
        mfmaset(2);
        rdA(cA, 3);
        mfmaset(3);
    }
    BARRIER();   // all compute done before smem repurposed by epilogue

    // ---- epilogue: per-wave 128x64 tile via wave-private 16KB LDS ----
    int m_base = by * 256 + wm * 128;
    int n_base = bx * 256 + wn * 64;
    char* myL = smem + wid * 16384;
    int which = n_base >> 10;                 // 0=q 1=k 2=v (uniform per wave)
    int h = (n_base & 1023) >> 6;
    int b = m_base >> 11, t0 = m_base & 2047;
    int bh = b * H_ + h;
    if (which == 2) {
        // stage C^T [64 dh][128 t] (256B rows), t sigma^-1-permuted in 32-blocks
#pragma unroll
        for (int m = 0; m < 8; m++)
#pragma unroll
            for (int n = 0; n < 4; n++) {
                int rd = n * 16 + lr;
                float bv = bias[n_base + rd];
#pragma unroll
                for (int j = 0; j < 4; j++) {
                    int ct = m * 16 + lk * 4 + j;
                    int ct2 = (ct & 96) | (((ct >> 2) & 3) << 3) | (((ct >> 4) & 1) << 2) | (ct & 3);
                    int addr = (rd * 256 + ct2 * 2) ^ ((rd & 7) << 4);
                    *(bf16_t*)(myL + addr) = (bf16_t)(acc[m][n][j] + bv);
                }
            }
#pragma unroll
        for (int it = 0; it < 16; it++) {
            int row = it * 4 + (lane >> 4);   // dh
            int byt = (lane & 15) * 16;
            bf16x8 val = *(const bf16x8*)(myL + ((row * 256 + byt) ^ ((row & 7) << 4)));
            *(bf16x8*)(vt_out + ((size_t)bh * DH_ + row) * T_ + t0 + (lane & 15) * 8) = val;
        }
    } else {
        bf16_t* dst = which ? k_out : q_out;
        float qscl = which ? 1.0f : 0.18033688011112042f;  // q: fold (1/8)*log2(e)
#pragma unroll
        for (int m = 0; m < 8; m++)
#pragma unroll
            for (int n = 0; n < 4; n++) {
                int dh = n * 16 + lr;
                float bv = bias[n_base + dh];
                int dh2 = dh >> 1;
                bool even = (dh & 1) == 0;
#pragma unroll
                for (int j = 0; j < 4; j++) {
                    int rt = m * 16 + lk * 4 + j;
                    float v = acc[m][n][j] + bv;
                    float pp = __shfl_xor(v, 1);           // partner dh^1 in lane^1
                    float2 cs = tab[(t0 + rt) * 32 + dh2];
                    float r = even ? v * cs.x - pp * cs.y : v * cs.x + pp * cs.y;
                    r *= qscl;
                    int addr = (rt * 128 + dh * 2) ^ ((rt & 7) << 4);
                    *(bf16_t*)(myL + addr) = (bf16_t)r;
                }
            }
#pragma unroll
        for (int it = 0; it < 16; it++) {
            int row = it * 8 + (lane >> 3);   // t_local
            int byt = (lane & 7) * 16;
            bf16x8 val = *(const bf16x8*)(myL + ((row * 128 + byt) ^ ((row & 7) << 4)));
            *(bf16x8*)(dst + ((size_t)bh * T_ + t0 + row) * DH_ + (lane & 7) * 8) = val;
        }
    }
}

// ---------------- 128x128 GEMM (out-proj), 3-deep counted-vmcnt pipeline -----
__global__ __launch_bounds__(256) void gemm128o(const bf16_t* __restrict__ A,
                                                const bf16_t* __restrict__ Bw,
                                                const float* __restrict__ bias,
                                                float* __restrict__ f_out,
                                                int K, int N) {
    __shared__ __align__(16) char smem[49152];
    char* b0 = smem;
    char* b1 = smem + 16384;
    char* b2 = smem + 32768;

    int tid = threadIdx.x;
    int lane = tid & 63, wid = tid >> 6;
    int wr = wid >> 1, wc = wid & 1;
    int lr = lane & 15, lk = lane >> 4;

    int l = blockIdx.y * gridDim.x + blockIdx.x;
    int chunk = (gridDim.x * gridDim.y) >> 3;
    int u = (l & 7) * chunk + (l >> 3);
    int bx = u % gridDim.x;
    int by = u / gridDim.x;

    f32x4 acc[4][4];
    f32x4 z = {0.f, 0.f, 0.f, 0.f};
#pragma unroll
    for (int i = 0; i < 4; i++)
#pragma unroll
        for (int j = 0; j < 4; j++) acc[i][j] = z;

    const char* Ab = (const char*)(A + (size_t)by * 128 * K);
    const char* Bb = (const char*)(Bw + (size_t)bx * 128 * K);
    const int rowstride = K * 2;

    int p0 = tid * 16;
    int p1 = 4096 + tid * 16;
    int r0 = p0 >> 6, r1 = p1 >> 6;
    int cb0 = (p0 & 63) ^ (((r0 >> 1) & 3) << 4);
    int cb1 = (p1 & 63) ^ (((r1 >> 1) & 3) << 4);
    size_t gA0 = (size_t)r0 * rowstride + cb0;
    size_t gA1 = (size_t)r1 * rowstride + cb1;

    int oa[4], ob[4];
#pragma unroll
    for (int m = 0; m < 4; m++) {
        int row = wr * 64 + m * 16 + lr;
        oa[m] = row * 64 + ((lk * 16) ^ (((row >> 1) & 3) << 4));
    }
#pragma unroll
    for (int n = 0; n < 4; n++) {
        int row = wc * 64 + n * 16 + lr;
        ob[n] = row * 64 + ((lk * 16) ^ (((row >> 1) & 3) << 4));
    }

    auto stg = [&](char* buf, int ks) __attribute__((always_inline)) {
        const char* Ag = Ab + (size_t)ks * 64;
        const char* Bg = Bb + (size_t)ks * 64;
        gld16(Ag + gA0, buf + p0);
        gld16(Ag + gA1, buf + p1);
        gld16(Bg + gA0, buf + 8192 + p0);
        gld16(Bg + gA1, buf + 8192 + p1);
    };

    auto iterf = [&](auto vmc, char* buf, int ks, bool dostage) __attribute__((always_inline)) {
        constexpr int VM = decltype(vmc)::value;
        if constexpr (VM == 8)      asm volatile("s_waitcnt vmcnt(8)" ::: "memory");
        else if constexpr (VM == 4) asm volatile("s_waitcnt vmcnt(4)" ::: "memory");
        else                        asm volatile("s_waitcnt vmcnt(0)" ::: "memory");
        __builtin_amdgcn_s_barrier();
        asm volatile("" ::: "memory");
        bf16x8 Af[4], Bf[4];
#pragma unroll
        for (int m = 0; m < 4; m++) Af[m] = *(const bf16x8*)(buf + oa[m]);
#pragma unroll
        for (int n = 0; n < 4; n++) Bf[n] = *(const bf16x8*)(buf + 8192 + ob[n]);
#pragma unroll
        for (int m = 0; m < 4; m++)
#pragma unroll
            for (int n = 0; n < 4; n++)
                acc[m][n] = __builtin_amdgcn_mfma_f32_16x16x32_bf16(Af[m], Bf[n], acc[m][n], 0, 0, 0);
        asm volatile("" ::: "memory");
        __builtin_amdgcn_s_barrier();
        asm volatile("" ::: "memory");
        if (dostage) stg(buf, ks);
    };

    std::integral_constant<int, 8> c8;
    std::integral_constant<int, 4> c4;
    std::integral_constant<int, 0> c0;

    stg(b0, 0);
    stg(b1, 1);
    stg(b2, 2);
    for (int s = 0; s < 30; s += 3) {
        iterf(c8, b0, s + 3, s + 3 < 32);
        iterf(c8, b1, s + 4, s + 4 < 32);
        iterf(c8, b2, s + 5, s + 5 < 32);
    }
    iterf(c4, b0, 0, false);
    iterf(c0, b1, 0, false);

    int m_base = by * 128 + wr * 64;
    int n_base = bx * 128 + wc * 64;
#pragma unroll
    for (int m = 0; m < 4; m++) {
        int gm0 = m_base + m * 16 + lk * 4;
#pragma unroll
        for (int n = 0; n < 4; n++) {
            int nc = n_base + n * 16 + lr;
            float bv = bias[nc];
#pragma unroll
            for (int j = 0; j < 4; j++)
                f_out[(size_t)(gm0 + j) * N + nc] = acc[m][n][j] + bv;
        }
    }
}

// ---------------- flash attention, S^T + QK/PV cross-tile pipeline -----------
__global__ __launch_bounds__(256, 4) void attn64(const bf16_t* __restrict__ Q,
                                                 const bf16_t* __restrict__ K,
                                                 const bf16_t* __restrict__ Vt,
                                                 bf16_t* __restrict__ Ao) {
    __shared__ __align__(16) char smem[40960];  // K0@0 K1@8K V0@16K V1@24K V2@32K

    int tid = threadIdx.x;
    int lane = tid & 63, wid = tid >> 6;
    int lr = lane & 15, lk = lane >> 4;
    int xcd = blockIdx.x & 7, idx = blockIdx.x >> 3;
    int bh = xcd * 4 + (idx & 3);
    int i5 = idx >> 2;                 // 0..31
    int qq = i5 & 7, rr = i5 >> 3;
    int qt = (rr == 0) ? qq : (rr == 1) ? 15 - qq : (rr == 2) ? 16 + qq : 31 - qq;
    int q0 = qt * 64;
    int qrel = wid * 16 + lr;

    const bf16_t* Qp = Q + ((size_t)bh * T_ + q0 + qrel) * DH_;
    bf16x8 qf0 = *(const bf16x8*)(Qp + lk * 8);
    bf16x8 qf1 = *(const bf16x8*)(Qp + 32 + lk * 8);

    f32x4 zz = {0.f, 0.f, 0.f, 0.f};
    f32x4 oacc[4];
#pragma unroll
    for (int dt = 0; dt < 4; dt++) oacc[dt] = zz;
    float mrun = -__builtin_inff(), lsum = 0.f;

    const char* Kbase = (const char*)(K + (size_t)bh * T_ * DH_);
    const char* Vbase = (const char*)(Vt + (size_t)bh * DH_ * T_);

    auto stage = [&](int s, char* Kd, char* Vd) __attribute__((always_inline)) {
        int kv0 = s * 64;
        const char* Kg = Kbase + (size_t)kv0 * 128;
#pragma unroll
        for (int c = 0; c < 2; c++) {
            int o = c * 4096 + tid * 16;
            int r = o >> 7;
            int g = o ^ ((r & 7) << 4);
            gld16(Kg + g, Kd + o);
            gld16(Vbase + (size_t)r * (T_ * 2) + kv0 * 2 + (g & 127), Vd + o);
        }
    };

    float p[4][4];
    bf16x8 pb0, pb1;

    auto do_qk = [&](const char* Kc, auto dmc) __attribute__((always_inline)) {
        constexpr bool DM = decltype(dmc)::value;
#pragma unroll
        for (int kt = 0; kt < 4; kt++) {
            int row = kt * 16 + lr;
            int key = (row & 7) << 4;
            bf16x8 kf0 = *(const bf16x8*)(Kc + ((row * 128 + lk * 16) ^ key));
            bf16x8 kf1 = *(const bf16x8*)(Kc + ((row * 128 + 64 + lk * 16) ^ key));
            f32x4 sacc = zz;
            sacc = __builtin_amdgcn_mfma_f32_16x16x32_bf16(kf0, qf0, sacc, 0, 0, 0);
            sacc = __builtin_amdgcn_mfma_f32_16x16x32_bf16(kf1, qf1, sacc, 0, 0, 0);
#pragma unroll
            for (int j = 0; j < 4; j++) {
                if (DM) {
                    int kvrel = kt * 16 + lk * 4 + j;
                    p[kt][j] = (kvrel <= qrel) ? sacc[j] : -__builtin_inff();
                } else {
                    p[kt][j] = sacc[j];
                }
            }
        }
    };

    auto do_pv = [&](const char* Vc) __attribute__((always_inline)) {
#pragma unroll
        for (int dt = 0; dt < 4; dt++) {
            int row = dt * 16 + lr;
            int key = (row & 7) << 4;
            bf16x8 vf0 = *(const bf16x8*)(Vc + ((row * 128 + lk * 16) ^ key));
            bf16x8 vf1 = *(const bf16x8*)(Vc + ((row * 128 + 64 + lk * 16) ^ key));
            f32x4 o = oacc[dt];
            o = __builtin_amdgcn_mfma_f32_16x16x32_bf16(vf0, pb0, o, 0, 0, 0);
            o = __builtin_amdgcn_mfma_f32_16x16x32_bf16(vf1, pb1, o, 0, 0, 0);
            oacc[dt] = o;
        }
    };

    auto do_softmax = [&]() __attribute__((always_inline)) {
        float mk[4];
#pragma unroll
        for (int kt = 0; kt < 4; kt++)
            mk[kt] = fmaxf(fmaxf(p[kt][0], p[kt][1]), fmaxf(p[kt][2], p[kt][3]));
        float mx = fmaxf(fmaxf(mk[0], mk[1]), fmaxf(mk[2], mk[3]));
        mx = fmaxf(mx, __shfl_xor(mx, 16));
        mx = fmaxf(mx, __shfl_xor(mx, 32));
        if (!__all(mx <= mrun + 8.f)) {
            float mnew = fmaxf(mrun, mx);
            float fac = exp2f(mrun - mnew);
            mrun = mnew;
            lsum *= fac;
#pragma unroll
            for (int dt = 0; dt < 4; dt++) oacc[dt] = oacc[dt] * fac;
        }
        float rs = 0.f;
#pragma unroll
        for (int kt = 0; kt < 4; kt++)
#pragma unroll
            for (int j = 0; j < 4; j++) {
                float e = exp2f(p[kt][j] - mrun);
                p[kt][j] = e;
                rs += e;
            }
        rs += __shfl_xor(rs, 16);
        rs += __shfl_xor(rs, 32);
        lsum += rs;
        pb0 = bf16x8{ (bf16_t)p[0][0], (bf16_t)p[0][1], (bf16_t)p[0][2], (bf16_t)p[0][3],
                      (bf16_t)p[1][0], (bf16_t)p[1][1], (bf16_t)p[1][2], (bf16_t)p[1][3] };
        pb1 = bf16x8{ (bf16_t)p[2][0], (bf16_t)p[2][1], (bf16_t)p[2][2], (bf16_t)p[2][3],
                      (bf16_t)p[3][0], (bf16_t)p[3][1], (bf16_t)p[3][2], (bf16_t)p[3][3] };
    };

    std::integral_constant<bool, true>  mask_y;
    std::integral_constant<bool, false> mask_n;

    stage(0, smem, smem + 16384);
    stage(1, smem + 8192, smem + 24576);
    asm volatile("s_waitcnt vmcnt(4)" ::: "memory");
    __builtin_amdgcn_s_barrier();
    asm volatile("" ::: "memory");
    if (qt == 0) do_qk(smem, mask_y); else do_qk(smem, mask_n);
    do_softmax();

    char* Kr = smem + 8192;
    char* Kw = smem;
    char* Vr = smem + 16384;
    char* Vn = smem + 24576;
    char* Vw = smem + 32768;

    auto iter = [&](int s, auto dmc) __attribute__((always_inline)) {
        asm volatile("s_waitcnt vmcnt(0)" ::: "memory");
        __builtin_amdgcn_s_barrier();
        asm volatile("" ::: "memory");
        if (s + 2 <= qt) stage(s + 2, Kw, Vw);
        do_qk(Kr, dmc);
        do_pv(Vr);
        do_softmax();
        char* t;
        t = Kr; Kr = Kw; Kw = t;
        t = Vr; Vr = Vn; Vn = Vw; Vw = t;
    };

    for (int s = 0; s + 1 < qt; ++s) iter(s, mask_n);
    if (qt > 0) iter(qt - 1, mask_y);
    do_pv(Vr);
    __syncthreads();

    char* myL = smem + wid * 2048;
    float rinv = __builtin_amdgcn_rcpf(lsum);
#pragma unroll
    for (int dt = 0; dt < 4; dt++)
#pragma unroll
        for (int j = 0; j < 4; j++) {
            int dh = dt * 16 + lk * 4 + j;
            int addr = (lr * 128 + dh * 2) ^ ((lr & 7) << 4);
            *(bf16_t*)(myL + addr) = (bf16_t)(oacc[dt][j] * rinv);
        }
    int b = bh >> 4, h = bh & 15;
#pragma unroll
    for (int it = 0; it < 2; it++) {
        int row = it * 8 + (lane >> 3);
        int byt = (lane & 7) * 16;
        bf16x8 val = *(const bf16x8*)(myL + ((row * 128 + byt) ^ ((row & 7) << 4)));
        int t = q0 + wid * 16 + row;
        *(bf16x8*)(Ao + ((size_t)b * T_ + t) * D_ + h * DH_ + (lane & 7) * 8) = val;
    }
}

// ---------------- launch ----------------
extern "C" void kernel_launch(void* const* d_in, const int* in_sizes, int n_in,
                              void* d_out, int out_size, void* d_ws, size_t ws_size,
                              hipStream_t stream) {
    const float* x     = (const float*)d_in[0];
    const float* w_qkv = (const float*)d_in[1];
    const float* b_qkv = (const float*)d_in[2];
    const float* w_out = (const float*)d_in[3];
    const float* b_out = (const float*)d_in[4];
    float* out = (float*)d_out;

    char* ws = (char*)d_ws;
    bf16_t* xb    = (bf16_t*)(ws);               //  8 MB  [4096][1024]
    bf16_t* wqkvb = (bf16_t*)(ws + 8388608);     //  6 MB  [3072][1024]
    bf16_t* wob   = (bf16_t*)(ws + 14680064);    //  2 MB  [1024][1024]
    bf16_t* qb    = (bf16_t*)(ws + 16777216);    //  8 MB  [32][2048][64] (pre-scaled)
    bf16_t* kb    = (bf16_t*)(ws + 25165824);    //  8 MB  [32][2048][64]
    bf16_t* vtb   = (bf16_t*)(ws + 33554432);    //  8 MB  [32][64][2048] (sigma-permuted t)
    bf16_t* ab    = (bf16_t*)(ws + 41943040);    //  8 MB  [4096][1024]
    float2* tab   = (float2*)(ws + 41943040);    // 512 KB RoPE table, lives in ab region

    cvt3<<<8448, 256, 0, stream>>>(x, w_qkv, w_out, xb, wqkvb, wob, tab);

    gemm256qkv<<<dim3(12, 16), 512, 0, stream>>>(xb, wqkvb, b_qkv, tab, qb, kb, vtb);
    attn64<<<1024, 256, 0, stream>>>(qb, kb, vtb, ab);
    gemm128o<<<dim3(8, 32), 256, 0, stream>>>(ab, wob, b_out, out, 1024, 1024);
}